// Round 6
// baseline (404.347 us; speedup 1.0000x reference)
//
#include <hip/hip_runtime.h>
#include <cstdint>
#include <cstddef>

#define NTOK 8192       // b*L = 2*4096

typedef __bf16 bf16x8 __attribute__((ext_vector_type(8)));
typedef float f32x4 __attribute__((ext_vector_type(4)));
typedef float f32x4v __attribute__((ext_vector_type(4)));
typedef unsigned short u16x8 __attribute__((ext_vector_type(8)));

__device__ __forceinline__ float b2f(unsigned short u) {
    return __uint_as_float(((unsigned int)u) << 16);
}
__device__ __forceinline__ unsigned short f2b(float f) {
    unsigned int u = __float_as_uint(f);
    u += 0x7FFFu + ((u >> 16) & 1u);   // round-nearest-even
    return (unsigned short)(u >> 16);
}

// async global->LDS, 16B per lane. LDS dest must be wave-uniform base + lane*16.
__device__ __forceinline__ void async_lds16(unsigned short* lds, const unsigned short* g) {
    __builtin_amdgcn_global_load_lds(
        (const __attribute__((address_space(1))) unsigned int*)g,
        (__attribute__((address_space(3))) unsigned int*)lds,
        16, 0, 0);
}

template <int N> __device__ __forceinline__ void waitcnt_vm() {
    if constexpr (N == 8)      asm volatile("s_waitcnt vmcnt(8)" ::: "memory");
    else if constexpr (N == 6) asm volatile("s_waitcnt vmcnt(6)" ::: "memory");
    else if constexpr (N == 4) asm volatile("s_waitcnt vmcnt(4)" ::: "memory");
    else if constexpr (N == 3) asm volatile("s_waitcnt vmcnt(3)" ::: "memory");
    else                       asm volatile("s_waitcnt vmcnt(0)" ::: "memory");
}

// ---- fused prep: x/W_in/W_B/W_C -> bf16 + scalars16 resolve (one launch) ----------
// grid 6145 x 256.  8-elem units: x 1048576 | W_in 262144 | W_B 131072 | W_C 131072.
// Segment boundaries are block-aligned (4096/1024/512/512 blocks); block 6144 = scalars.
__global__ __launch_bounds__(256) void prep(
    const float* __restrict__ x, const float* __restrict__ W_in,
    const float* __restrict__ W_B, const float* __restrict__ W_C,
    unsigned short* __restrict__ xb, unsigned short* __restrict__ Wst,
    const float* __restrict__ s16a, const float* __restrict__ s16b,
    float* __restrict__ alogf, float* __restrict__ bdtf)
{
    const long i = (long)blockIdx.x * 256 + threadIdx.x;
    const float* src; unsigned short* dst; long off;
    if (i < 1048576)      { src = x;    dst = xb;            off = i; }
    else if (i < 1310720) { src = W_in; dst = Wst;           off = i - 1048576; }
    else if (i < 1441792) { src = W_B;  dst = Wst + 2097152; off = i - 1310720; }
    else if (i < 1572864) { src = W_C;  dst = Wst + 3145728; off = i - 1441792; }
    else {
        if (i == 1572864) {   // block 6144, thread 0: resolve A_log vs b_dt
            float ma = 0.f, mb = 0.f;
            for (int k = 0; k < 16; k++) { ma = fmaxf(ma, fabsf(s16a[k])); mb = fmaxf(mb, fabsf(s16b[k])); }
            const float* alog = (ma >= mb) ? s16a : s16b;
            const float* bdt  = (ma >= mb) ? s16b : s16a;
            for (int k = 0; k < 16; k++) { alogf[k] = alog[k]; bdtf[k] = bdt[k]; }
        }
        return;
    }
    const f32x4v* p = (const f32x4v*)(src + off * 8);
    f32x4v a = p[0], b = p[1];
    u16x8 v;
#pragma unroll
    for (int t = 0; t < 4; t++) { v[t] = f2b(a[t]); v[t + 4] = f2b(b[t]); }
    *(u16x8*)(dst + off * 8) = v;
}

// ---- fp32 -> bf16 bulk convert (8 elems/thread) — still used for W_out ------------
__global__ __launch_bounds__(256) void f32_to_bf16(
    const float* __restrict__ in, unsigned short* __restrict__ out, int n8)
{
    const int i = blockIdx.x * 256 + threadIdx.x;
    if (i >= n8) return;
    const f32x4v* p = (const f32x4v*)(in + (long)i * 8);
    f32x4v a = p[0], b = p[1];
    u16x8 v;
#pragma unroll
    for (int t = 0; t < 4; t++) { v[t] = f2b(a[t]); v[t + 4] = f2b(b[t]); }
    *(u16x8*)(out + (long)i * 8) = v;
}

// ---------------- dt kernel: one thread per (token, head), fp32, float4 loads ------
__global__ __launch_bounds__(256) void dt_kernel(
    const float* __restrict__ x, const float* __restrict__ Wdt,
    const float* __restrict__ bdt, const float* __restrict__ Alog,
    float* __restrict__ dtp, float* __restrict__ Ap)
{
    const int token = blockIdx.x * 16 + (threadIdx.x >> 4);
    const int h = threadIdx.x & 15;
    const f32x4v* xr = (const f32x4v*)(x + (long)token * 1024);
    const f32x4v* wr = (const f32x4v*)(Wdt + h * 1024);
    float s0 = bdt[h], s1 = 0.f;
#pragma unroll 8
    for (int k = 0; k < 256; k += 2) {
        f32x4v a0 = xr[k], w0 = wr[k];
        f32x4v a1 = xr[k + 1], w1 = wr[k + 1];
        s0 += a0[0] * w0[0] + a0[1] * w0[1] + a0[2] * w0[2] + a0[3] * w0[3];
        s1 += a1[0] * w1[0] + a1[1] * w1[1] + a1[2] * w1[2] + a1[3] * w1[3];
    }
    const float s = s0 + s1;
    const float dtv = (s > 15.f) ? s : log1pf(expf(s));
    dtp[token * 16 + h] = dtv;
    Ap[token * 16 + h] = -expf(Alog[h]) * dtv;
}

// ------- 256xBN-tile BK=32 4-buffer counted-vmcnt MFMA GEMM (T4 pipeline) ----------
// Out[M,N] = A[M,K] @ W[N,K]^T.  512 threads = 8 waves (2M x 4N); NI=4 -> BN=256
// (wave owns 128x64), NI=2 -> BN=128 (wave owns 128x32).
// BK=32: LDS row stride 64B -> fragment ds_read_b128 pattern is conflict-free with
// a LINEAR layout (rows alias 16 banks apart, quad covers the rest) -> no swizzle.
// Pipeline: 4 LDS buffers, tiles t+1..t+3 in flight; per-tile `s_waitcnt vmcnt(2*LPT)`
// + raw s_barrier (never drain-0 in the main loop). Epilogue waits LPT -> 0.
// MODE 0: fp32 out0 (stride N).
// MODE 1 (merged xz+BC over stacked W = [W_in; W_B; W_C], N=4096):
//   seg0: X = acc*dt (bf16 out0); seg1: SZ = silu (out1); seg2: Bb (out2); seg3: Cb (out3)
template <int MODE, int NI>
__global__ __launch_bounds__(512, 2) void gemm256(
    const unsigned short* __restrict__ A, const unsigned short* __restrict__ W,
    const int NT_N, const int N, const int K,
    void* __restrict__ out0, unsigned short* __restrict__ out1,
    unsigned short* __restrict__ out2, unsigned short* __restrict__ out3,
    const float* __restrict__ dtp)
{
    constexpr int BN = NI * 64;          // 256 or 128
    constexpr int LPT = 2 + NI / 2;      // loads/thread/tile: A=2, W=NI/2

    __shared__ unsigned short As[4][256 * 32];
    __shared__ unsigned short Ws[4][BN * 32];

    const int tid = threadIdx.x;
    const int lane = tid & 63;
    const int warp = tid >> 6;      // 0..7
    const int wm = warp >> 2;       // 0..1
    const int wn = warp & 3;        // 0..3
    const int qm = lane & 15;
    const int quad = lane >> 4;

    // T1: bijective XCD-aware swizzle (gridDim.x % 8 == 0 for all our grids)
    const int nwg = gridDim.x;
    const int cpx = nwg >> 3;
    const int bid = blockIdx.x;
    const int swz = (bid & 7) * cpx + (bid >> 3);
    const int bx = swz % NT_N;
    const int by = swz / NT_N;
    const long arow0 = (long)by * 256;
    const long wrow0 = (long)bx * BN;

    // staging: thread covers row = i*128 + (tid>>2), col group (tid&3)*8 (16B)
    const int srow = tid >> 2;           // 0..127 (+ i*128)
    const int scol = (tid & 3) * 8;

    f32x4 acc[8][NI];
    const f32x4 zero = {0.f, 0.f, 0.f, 0.f};
#pragma unroll
    for (int i = 0; i < 8; i++)
#pragma unroll
        for (int j = 0; j < NI; j++) acc[i][j] = zero;

    auto stage = [&](int buf, int k0) {
#pragma unroll
        for (int i = 0; i < 2; i++)
            async_lds16(As[buf] + i * 4096 + tid * 8,
                        A + (arow0 + i * 128 + srow) * (long)K + k0 + scol);
#pragma unroll
        for (int i = 0; i < NI / 2; i++)
            async_lds16(Ws[buf] + i * 4096 + tid * 8,
                        W + (wrow0 + i * 128 + srow) * (long)K + k0 + scol);
    };
    auto compute = [&](const unsigned short* Ab, const unsigned short* Wb) {
        bf16x8 fa[8], fb[NI];
#pragma unroll
        for (int mi = 0; mi < 8; mi++)
            fa[mi] = *(const bf16x8*)(Ab + (wm * 128 + mi * 16 + qm) * 32 + quad * 8);
#pragma unroll
        for (int ni = 0; ni < NI; ni++)
            fb[ni] = *(const bf16x8*)(Wb + (wn * (NI * 16) + ni * 16 + qm) * 32 + quad * 8);
#pragma unroll
        for (int mi = 0; mi < 8; mi++)
#pragma unroll
            for (int ni = 0; ni < NI; ni++)
                acc[mi][ni] = __builtin_amdgcn_mfma_f32_16x16x32_bf16(
                    fa[mi], fb[ni], acc[mi][ni], 0, 0, 0);
    };

    const int nt = K >> 5;               // 32 for K=1024
    stage(0, 0); stage(1, 32); stage(2, 64);
    waitcnt_vm<2 * LPT>(); __builtin_amdgcn_s_barrier();   // tile0 retired
    int t = 0;
    for (; t < nt - 3; ++t) {
        stage((t + 3) & 3, (t + 3) << 5);   // overwrite buf freed at iter t-1's barrier
        compute(As[t & 3], Ws[t & 3]);
        waitcnt_vm<2 * LPT>(); __builtin_amdgcn_s_barrier();   // tile t+1 retired
    }
    compute(As[t & 3], Ws[t & 3]); waitcnt_vm<LPT>(); __builtin_amdgcn_s_barrier(); ++t;
    compute(As[t & 3], Ws[t & 3]); waitcnt_vm<0>();   __builtin_amdgcn_s_barrier(); ++t;
    compute(As[t & 3], Ws[t & 3]);

    // epilogue: C/D layout col=lane&15, row=quad*4+reg (verified m89/m91)
#pragma unroll
    for (int mi = 0; mi < 8; mi++)
#pragma unroll
        for (int ni = 0; ni < NI; ni++)
#pragma unroll
            for (int r = 0; r < 4; r++) {
                const long row = arow0 + wm * 128 + mi * 16 + quad * 4 + r;
                const int col = (int)wrow0 + wn * (NI * 16) + ni * 16 + qm;
                const float v = acc[mi][ni][r];
                if (MODE == 0) {
                    ((float*)out0)[row * N + col] = v;
                } else {
                    const int seg = col >> 10, cc = col & 1023;
                    if (seg == 0) {
                        ((unsigned short*)out0)[row * 1024 + cc] = f2b(v * dtp[row * 16 + (cc >> 6)]);
                    } else if (seg == 1) {
                        out1[row * 1024 + cc] = f2b(v / (1.f + expf(-v)));
                    } else if (seg == 2) {
                        out2[row * 1024 + cc] = f2b(v);
                    } else {
                        out3[row * 1024 + cc] = f2b(v);
                    }
                }
            }
}

// ---------------- phase A (MFMA): per-chunk states -> d_out (fp32) + Alast ---------
// st[p,n] = sum_l (X[l,p]*dec[l]) * B[l,n].  Contraction over l (row of both) ->
// both operands staged TRANSPOSED in LDS. X*dec split hi/lo bf16 for fp32 fidelity.
__global__ __launch_bounds__(256) void ssd_states(
    const unsigned short* __restrict__ Xb, const unsigned short* __restrict__ Bb,
    const float* __restrict__ Ap, float* __restrict__ st_out,
    float* __restrict__ Alast)
{
    __shared__ __align__(16) unsigned short Xh[64 * 64];
    __shared__ __align__(16) unsigned short Xl[64 * 64];
    __shared__ __align__(16) unsigned short Bt[64 * 64];
    __shared__ float Acum[64];
    __shared__ float dec[64];

    const int blk = blockIdx.x;                 // blk = (b*64 + c)*16 + h
    const int h = blk & 15;
    const int c = (blk >> 4) & 63;
    const int b = blk >> 10;
    const long tokenbase = (long)b * 4096 + (long)c * 64;
    const int tid = threadIdx.x;
    const int lane = tid & 63;
    const int w = tid >> 6;
    const int qm = lane & 15;
    const int quad = lane >> 4;

    if (tid < 64) Acum[tid] = Ap[(tokenbase + tid) * 16 + h];

    // preload to regs (row-fast mapping: lane = token row, L1 soaks the stride)
    const int row = tid & 63;
    u16x8 rx[2], rb[2];
#pragma unroll
    for (int i = 0; i < 2; i++) {
        const int ch = (tid >> 6) + 4 * i;      // 0..7 over 2 iters
        const long g = (tokenbase + row) * 1024 + h * 64 + ch * 8;
        rx[i] = *(const u16x8*)(Xb + g);
        rb[i] = *(const u16x8*)(Bb + g);
    }
    __syncthreads();
    if (tid == 0) {
        float s = 0.f;
        for (int l = 0; l < 64; l++) { s += Acum[l]; Acum[l] = s; }
        Alast[(b * 16 + h) * 64 + c] = s;
    }
    __syncthreads();
    if (tid < 64) dec[tid] = expf(Acum[63] - Acum[tid]);
    __syncthreads();

    const float dv = dec[row];
#pragma unroll
    for (int i = 0; i < 2; i++) {
        const int ch = (tid >> 6) + 4 * i;
#pragma unroll
        for (int t = 0; t < 8; t++) {
            const int pn = ch * 8 + t;
            const int d = (pn * 64 + row) ^ (t << 3);   // (pn&7)==t
            const float xd = b2f(rx[i][t]) * dv;
            const unsigned short hi = f2b(xd);
            Xh[d] = hi;
            Xl[d] = f2b(xd - b2f(hi));
            Bt[d] = rb[i][t];
        }
    }
    __syncthreads();

    // wave w owns p-strip [16w, 16w+16)
    f32x4 acc[4];
    const f32x4 zero = {0.f, 0.f, 0.f, 0.f};
#pragma unroll
    for (int ni = 0; ni < 4; ni++) acc[ni] = zero;
#pragma unroll
    for (int kk2 = 0; kk2 < 2; kk2++) {
        const int ko = kk2 * 32 + quad * 8;
        const int ra = 16 * w + qm;
        const int da = (ra * 64 + ko) ^ ((ra & 7) << 3);
        bf16x8 fxh = *(const bf16x8*)(Xh + da);
        bf16x8 fxl = *(const bf16x8*)(Xl + da);
#pragma unroll
        for (int ni = 0; ni < 4; ni++) {
            const int rn = ni * 16 + qm;
            bf16x8 fb = *(const bf16x8*)(Bt + ((rn * 64 + ko) ^ ((rn & 7) << 3)));
            acc[ni] = __builtin_amdgcn_mfma_f32_16x16x32_bf16(fxh, fb, acc[ni], 0, 0, 0);
            acc[ni] = __builtin_amdgcn_mfma_f32_16x16x32_bf16(fxl, fb, acc[ni], 0, 0, 0);
        }
    }
    const long sbase = (long)blk * 4096;
    const int p0 = 16 * w + quad * 4;
#pragma unroll
    for (int ni = 0; ni < 4; ni++)
#pragma unroll
        for (int r = 0; r < 4; r++)
            st_out[sbase + (p0 + r) * 64 + ni * 16 + qm] = acc[ni][r];
}

// ---------------- inter-chunk scan (in place, fp32 in d_out) + final_state ---------
__global__ __launch_bounds__(256) void scan_kernel(
    float* __restrict__ st, const float* __restrict__ Alast)
{
    const int blk = blockIdx.x;          // 512 blocks: b(2) x h(16) x grp(16)
    const int grp = blk & 15;
    const int h = (blk >> 4) & 15;
    const int b = blk >> 8;
    const int e = grp * 256 + threadIdx.x;
    const float* al = Alast + (b * 16 + h) * 64;
    float M = 0.f;
    for (int c = 0; c < 64; c++) {
        const long idx = ((long)((b * 64 + c) * 16 + h)) * 4096 + e;
        const float s = st[idx];
        st[idx] = M;                     // state ENTERING chunk c
        M = expf(al[c]) * M + s;
    }
    st[(long)8388608 + (long)(b * 16 + h) * 4096 + e] = M;   // final_state (fp32)
}

// ---------------- phase B (MFMA): Y_diag + Y_off + silu gate (in-place into SZ) ----
// T[l,s]=sum_n C[l,n]B[s,n]; off[l,p]=sum_n C[l,n]S[p,n]; Y[l,p]=sum_s G[l,s]X[s,p].
// X staged transposed (Xt[p][s]); G written by each wave for its own strip.
__global__ __launch_bounds__(256) void ssd_yoff(
    const unsigned short* __restrict__ Xb, const unsigned short* __restrict__ Bb,
    const unsigned short* __restrict__ Cb, const float* __restrict__ Ap,
    const float* __restrict__ st, unsigned short* __restrict__ SZb)
{
    __shared__ __align__(16) unsigned short Bs[64 * 64];
    __shared__ __align__(16) unsigned short Ss[64 * 64];
    __shared__ __align__(16) unsigned short Xt[64 * 64];
    __shared__ __align__(16) unsigned short Gs[64 * 64];
    __shared__ float Acum[64];

    const int blk = blockIdx.x;
    const int h = blk & 15;
    const int c = (blk >> 4) & 63;
    const int b = blk >> 10;
    const long tokenbase = (long)b * 4096 + (long)c * 64;
    const int tid = threadIdx.x;
    const int lane = tid & 63;
    const int w = tid >> 6;
    const int qm = lane & 15;
    const int quad = lane >> 4;
    const long sbase = (long)blk * 4096;

    if (tid < 64) Acum[tid] = Ap[(tokenbase + tid) * 16 + h];

    // stage B (natural, swizzled) and S (fp32 states -> bf16, natural, swizzled)
#pragma unroll
    for (int i = 0; i < 2; i++) {
        const int idx = tid + i * 256;
        const int r8 = idx >> 3, c8 = (idx & 7) * 8;
        const long g = (tokenbase + r8) * 1024 + h * 64 + c8;
        const int d = (r8 * 64 + c8) ^ ((r8 & 7) << 3);
        *(u16x8*)(Bs + d) = *(const u16x8*)(Bb + g);
        const float* sp = st + sbase + r8 * 64 + c8;
        f32x4v s0 = *(const f32x4v*)sp, s1 = *(const f32x4v*)(sp + 4);
        u16x8 sv;
#pragma unroll
        for (int t = 0; t < 4; t++) { sv[t] = f2b(s0[t]); sv[t + 4] = f2b(s1[t]); }
        *(u16x8*)(Ss + d) = sv;
    }
    // stage Xt (transposed, row-fast mapping)
    const int xrow = tid & 63;
#pragma unroll
    for (int i = 0; i < 2; i++) {
        const int ch = (tid >> 6) + 4 * i;
        const long g = (tokenbase + xrow) * 1024 + h * 64 + ch * 8;
        u16x8 xv = *(const u16x8*)(Xb + g);
#pragma unroll
        for (int t = 0; t < 8; t++) {
            const int p = ch * 8 + t;
            Xt[(p * 64 + xrow) ^ (t << 3)] = xv[t];
        }
    }
    // C fragments direct from global (wave-private rows 16w+qm)
    u16x8 fc[2];
#pragma unroll
    for (int kk2 = 0; kk2 < 2; kk2++)
        fc[kk2] = *(const u16x8*)(Cb + (tokenbase + 16 * w + qm) * 1024 + h * 64 + kk2 * 32 + quad * 8);

    __syncthreads();
    if (tid == 0) {
        float s = 0.f;
        for (int l = 0; l < 64; l++) { s += Acum[l]; Acum[l] = s; }
    }

    // matmul1 (T = C.B^T) and matmul2 (off = C.S^T), wave strip l in [16w,16w+16)
    f32x4 acc1[4], acc2[4];
    const f32x4 zero = {0.f, 0.f, 0.f, 0.f};
#pragma unroll
    for (int ni = 0; ni < 4; ni++) { acc1[ni] = zero; acc2[ni] = zero; }
#pragma unroll
    for (int kk2 = 0; kk2 < 2; kk2++) {
        const int ko = kk2 * 32 + quad * 8;
        bf16x8 fa = *(const bf16x8*)&fc[kk2];
#pragma unroll
        for (int ni = 0; ni < 4; ni++) {
            const int rn = ni * 16 + qm;
            const int d = (rn * 64 + ko) ^ ((rn & 7) << 3);
            bf16x8 fbb = *(const bf16x8*)(Bs + d);
            acc1[ni] = __builtin_amdgcn_mfma_f32_16x16x32_bf16(fa, fbb, acc1[ni], 0, 0, 0);
            bf16x8 fbs = *(const bf16x8*)(Ss + d);
            acc2[ni] = __builtin_amdgcn_mfma_f32_16x16x32_bf16(fa, fbs, acc2[ni], 0, 0, 0);
        }
    }
    __syncthreads();   // Acum (prefix) now visible to all

    // G[l,s] = (s<=l) ? T[l,s]*exp(Acum[l]-Acum[s]) : 0  -> LDS bf16 (swizzled)
    const int l0 = 16 * w + quad * 4;
    float al[4];
#pragma unroll
    for (int r = 0; r < 4; r++) al[r] = Acum[l0 + r];
#pragma unroll
    for (int ni = 0; ni < 4; ni++) {
        const int s = ni * 16 + qm;
        const float as = Acum[s];
#pragma unroll
        for (int r = 0; r < 4; r++) {
            const int l = l0 + r;
            const float gv = (s <= l) ? acc1[ni][r] * expf(al[r] - as) : 0.f;
            Gs[(l * 64 + s) ^ ((l & 7) << 3)] = f2b(gv);
        }
    }
    __syncthreads();

    // matmul3: Y = G @ X  (A = G own strip, B = Xt)
    f32x4 acc3[4];
#pragma unroll
    for (int ni = 0; ni < 4; ni++) acc3[ni] = zero;
#pragma unroll
    for (int kk2 = 0; kk2 < 2; kk2++) {
        const int ko = kk2 * 32 + quad * 8;
        const int ra = 16 * w + qm;
        bf16x8 fg = *(const bf16x8*)(Gs + ((ra * 64 + ko) ^ ((ra & 7) << 3)));
#pragma unroll
        for (int ni = 0; ni < 4; ni++) {
            const int rp = ni * 16 + qm;
            bf16x8 fx = *(const bf16x8*)(Xt + ((rp * 64 + ko) ^ ((rp & 7) << 3)));
            acc3[ni] = __builtin_amdgcn_mfma_f32_16x16x32_bf16(fg, fx, acc3[ni], 0, 0, 0);
        }
    }
    // epilogue: Y = Y_diag + exp(Acum[l])*off; gate with silu(z) already in SZ
    float eds[4];
#pragma unroll
    for (int r = 0; r < 4; r++) eds[r] = expf(al[r]);
#pragma unroll
    for (int ni = 0; ni < 4; ni++) {
#pragma unroll
        for (int r = 0; r < 4; r++) {
            const int l = l0 + r;
            const int p = ni * 16 + qm;
            const float Y = acc3[ni][r] + eds[r] * acc2[ni][r];
            const long o = (tokenbase + l) * 1024 + h * 64 + p;
            SZb[o] = f2b(Y * b2f(SZb[o]));
        }
    }
}

// ---------------- launch -----------------------------------------------------------
extern "C" void kernel_launch(void* const* d_in, const int* in_sizes, int n_in,
                              void* d_out, int out_size, void* d_ws, size_t ws_size,
                              hipStream_t stream)
{
    int ix = 0, iwin = 1, iwdt = 2, i1m[3] = {4, 5, 6}, n1m = 0, i16[2] = {3, 7}, n16 = 0;
    for (int i = 0; i < n_in; i++) {
        switch (in_sizes[i]) {
            case 8388608: ix = i; break;
            case 2097152: iwin = i; break;
            case 16384:   iwdt = i; break;
            case 1048576: if (n1m < 3) i1m[n1m++] = i; break;
            case 16:      if (n16 < 2) i16[n16++] = i; break;
            default: break;
        }
    }
    if (n1m < 3) { i1m[0] = 4; i1m[1] = 5; i1m[2] = 6; }
    if (n16 < 2) { i16[0] = 3; i16[1] = 7; }
    const float* x     = (const float*)d_in[ix];
    const float* W_in  = (const float*)d_in[iwin];
    const float* W_dt  = (const float*)d_in[iwdt];
    const float* W_B   = (const float*)d_in[i1m[0]];
    const float* W_C   = (const float*)d_in[i1m[1]];
    const float* W_out = (const float*)d_in[i1m[2]];
    const float* s16a  = (const float*)d_in[i16[0]];
    const float* s16b  = (const float*)d_in[i16[1]];
    float* out = (float*)d_out;

    char* ws = (char*)d_ws;
    float* dtp   = (float*)(ws);                              // 512 KB @0
    float* Ap    = (float*)(ws + 524288);                     // 512 KB
    float* Alast = (float*)(ws + 1048576);                    // 8 KB
    float* Alogf = (float*)(ws + 1056768);                    // 64 B
    float* bdtf  = (float*)(ws + 1056832);                    // 64 B
    unsigned short* Xb  = (unsigned short*)(ws + 2097152);    // 16 MB
    unsigned short* Bb  = (unsigned short*)(ws + 18874368);   // 16 MB
    unsigned short* Cb  = (unsigned short*)(ws + 35651584);   // 16 MB
    unsigned short* SZb = (unsigned short*)(ws + 52428800);   // 16 MB  (end: 68 MB)

    // d_out[0:32MB) is dead until ssd_states: use it for bf16 conversions.
    // xb 16MB | stacked W bf16 [W_in(2048) ; W_B(1024) ; W_C(1024)] = 8MB -> 24MB < 32MB
    unsigned short* xb  = (unsigned short*)d_out;
    unsigned short* Wst = (unsigned short*)((char*)d_out + 16777216);
    // W_out bf16: converted AFTER ssd_yoff into the then-dead Xb ws region.
    unsigned short* Wob = Xb;

    // fp32 chunk states use d_out[0:8388608 floats) as scratch (xb/weights dead by then);
    // final_state fp32 at d_out[8388608:]; final GEMM overwrites y region.
    float* states = out;

    prep<<<6145, 256, 0, stream>>>(x, W_in, W_B, W_C, xb, Wst, s16a, s16b, Alogf, bdtf);
    dt_kernel<<<NTOK / 16, 256, 0, stream>>>(x, W_dt, bdtf, Alogf, dtp, Ap);
    // merged xz + B + C GEMM: M=8192, N=4096, K=1024; grid 32x16 = 512 blocks
    gemm256<1, 4><<<512, 512, 0, stream>>>(xb, Wst, 16, 4096, 1024, Xb, SZb, Bb, Cb, dtp);
    ssd_states<<<2048, 256, 0, stream>>>(Xb, Bb, Ap, states, Alast);
    scan_kernel<<<512, 256, 0, stream>>>(states, Alast);
    ssd_yoff<<<2048, 256, 0, stream>>>(Xb, Bb, Cb, Ap, states, SZb);
    f32_to_bf16<<<512, 256, 0, stream>>>(W_out, Wob, 131072);         // W_out -> bf16 (Xb dead)
    // final GEMM: M=8192, N=1024, K=1024, BN=128; grid 32x8 = 256 blocks (1 full round)
    gemm256<0, 2><<<256, 512, 0, stream>>>(SZb, Wob, 8, 1024, 1024, out, nullptr, nullptr, nullptr, nullptr);
}

// Round 7
// 380.365 us; speedup vs baseline: 1.0631x; 1.0631x over previous
//
#include <hip/hip_runtime.h>
#include <cstdint>
#include <cstddef>

#define NTOK 8192       // b*L = 2*4096

typedef __bf16 bf16x8 __attribute__((ext_vector_type(8)));
typedef float f32x4 __attribute__((ext_vector_type(4)));
typedef float f32x4v __attribute__((ext_vector_type(4)));
typedef unsigned short u16x8 __attribute__((ext_vector_type(8)));

__device__ __forceinline__ float b2f(unsigned short u) {
    return __uint_as_float(((unsigned int)u) << 16);
}
__device__ __forceinline__ unsigned short f2b(float f) {
    unsigned int u = __float_as_uint(f);
    u += 0x7FFFu + ((u >> 16) & 1u);   // round-nearest-even
    return (unsigned short)(u >> 16);
}

// async global->LDS, 16B per lane. LDS dest must be wave-uniform base + lane*16.
__device__ __forceinline__ void async_lds16(unsigned short* lds, const unsigned short* g) {
    __builtin_amdgcn_global_load_lds(
        (const __attribute__((address_space(1))) unsigned int*)g,
        (__attribute__((address_space(3))) unsigned int*)lds,
        16, 0, 0);
}

template <int N> __device__ __forceinline__ void waitcnt_vm() {
    if constexpr (N == 8)      asm volatile("s_waitcnt vmcnt(8)" ::: "memory");
    else if constexpr (N == 6) asm volatile("s_waitcnt vmcnt(6)" ::: "memory");
    else if constexpr (N == 4) asm volatile("s_waitcnt vmcnt(4)" ::: "memory");
    else if constexpr (N == 3) asm volatile("s_waitcnt vmcnt(3)" ::: "memory");
    else                       asm volatile("s_waitcnt vmcnt(0)" ::: "memory");
}

// ---- fused prep: x/W_in/W_B/W_C -> bf16 + scalars16 resolve (one launch) ----------
// grid 6145 x 256.  8-elem units: x 1048576 | W_in 262144 | W_B 131072 | W_C 131072.
// Segment boundaries are block-aligned (4096/1024/512/512 blocks); block 6144 = scalars.
__global__ __launch_bounds__(256) void prep(
    const float* __restrict__ x, const float* __restrict__ W_in,
    const float* __restrict__ W_B, const float* __restrict__ W_C,
    unsigned short* __restrict__ xb, unsigned short* __restrict__ Wst,
    const float* __restrict__ s16a, const float* __restrict__ s16b,
    float* __restrict__ alogf, float* __restrict__ bdtf)
{
    const long i = (long)blockIdx.x * 256 + threadIdx.x;
    const float* src; unsigned short* dst; long off;
    if (i < 1048576)      { src = x;    dst = xb;            off = i; }
    else if (i < 1310720) { src = W_in; dst = Wst;           off = i - 1048576; }
    else if (i < 1441792) { src = W_B;  dst = Wst + 2097152; off = i - 1310720; }
    else if (i < 1572864) { src = W_C;  dst = Wst + 3145728; off = i - 1441792; }
    else {
        if (i == 1572864) {   // block 6144, thread 0: resolve A_log vs b_dt
            float ma = 0.f, mb = 0.f;
            for (int k = 0; k < 16; k++) { ma = fmaxf(ma, fabsf(s16a[k])); mb = fmaxf(mb, fabsf(s16b[k])); }
            const float* alog = (ma >= mb) ? s16a : s16b;
            const float* bdt  = (ma >= mb) ? s16b : s16a;
            for (int k = 0; k < 16; k++) { alogf[k] = alog[k]; bdtf[k] = bdt[k]; }
        }
        return;
    }
    const f32x4v* p = (const f32x4v*)(src + off * 8);
    f32x4v a = p[0], b = p[1];
    u16x8 v;
#pragma unroll
    for (int t = 0; t < 4; t++) { v[t] = f2b(a[t]); v[t + 4] = f2b(b[t]); }
    *(u16x8*)(dst + off * 8) = v;
}

// ---- fp32 -> bf16 bulk convert (8 elems/thread) — still used for W_out ------------
__global__ __launch_bounds__(256) void f32_to_bf16(
    const float* __restrict__ in, unsigned short* __restrict__ out, int n8)
{
    const int i = blockIdx.x * 256 + threadIdx.x;
    if (i >= n8) return;
    const f32x4v* p = (const f32x4v*)(in + (long)i * 8);
    f32x4v a = p[0], b = p[1];
    u16x8 v;
#pragma unroll
    for (int t = 0; t < 4; t++) { v[t] = f2b(a[t]); v[t + 4] = f2b(b[t]); }
    *(u16x8*)(out + (long)i * 8) = v;
}

// ---------------- dt kernel: one thread per (token, head), fp32, float4 loads ------
__global__ __launch_bounds__(256) void dt_kernel(
    const float* __restrict__ x, const float* __restrict__ Wdt,
    const float* __restrict__ bdt, const float* __restrict__ Alog,
    float* __restrict__ dtp, float* __restrict__ Ap)
{
    const int token = blockIdx.x * 16 + (threadIdx.x >> 4);
    const int h = threadIdx.x & 15;
    const f32x4v* xr = (const f32x4v*)(x + (long)token * 1024);
    const f32x4v* wr = (const f32x4v*)(Wdt + h * 1024);
    float s0 = bdt[h], s1 = 0.f;
#pragma unroll 8
    for (int k = 0; k < 256; k += 2) {
        f32x4v a0 = xr[k], w0 = wr[k];
        f32x4v a1 = xr[k + 1], w1 = wr[k + 1];
        s0 += a0[0] * w0[0] + a0[1] * w0[1] + a0[2] * w0[2] + a0[3] * w0[3];
        s1 += a1[0] * w1[0] + a1[1] * w1[1] + a1[2] * w1[2] + a1[3] * w1[3];
    }
    const float s = s0 + s1;
    const float dtv = (s > 15.f) ? s : log1pf(expf(s));
    dtp[token * 16 + h] = dtv;
    Ap[token * 16 + h] = -expf(Alog[h]) * dtv;
}

// ------- 256xBN-tile BK=32 4-buffer counted-vmcnt MFMA GEMM (T4 + T2 swizzle) ------
// Out[M,N] = A[M,K] @ W[N,K]^T.  512 threads = 8 waves (2M x 4N); NI=4 -> BN=256
// (wave owns 128x64), NI=2 -> BN=128 (wave owns 128x32).
// T2 swizzle (both-sides involution on 16B groups, swz(row) = (row>>1)&3):
//   write: LDS dest LINEAR (global_load_lds), global src group = (tid&3)^((srow>>1)&3)
//          (permutes within the row's 64B segment -> coalescing preserved)
//   read:  group = quad ^ ((qm>>1)&3)  (fragment rows ...*16+qm -> swz = (qm>>1)&3)
//   bank check: 16 lanes/quad cover all 8 bank-groups x2 = free (m136). Bit-identical.
// Pipeline: 4 LDS buffers, tiles t+1..t+3 in flight; per-tile `s_waitcnt vmcnt(2*LPT)`
// + raw s_barrier (never drain-0 in the main loop). Epilogue waits LPT -> 0.
// MODE 0: fp32 out0 (stride N).
// MODE 1 (merged xz+BC over stacked W = [W_in; W_B; W_C], N=4096):
//   seg0: X = acc*dt (bf16 out0); seg1: SZ = silu (out1); seg2: Bb (out2); seg3: Cb (out3)
template <int MODE, int NI>
__global__ __launch_bounds__(512, 2) void gemm256(
    const unsigned short* __restrict__ A, const unsigned short* __restrict__ W,
    const int NT_N, const int N, const int K,
    void* __restrict__ out0, unsigned short* __restrict__ out1,
    unsigned short* __restrict__ out2, unsigned short* __restrict__ out3,
    const float* __restrict__ dtp)
{
    constexpr int BN = NI * 64;          // 256 or 128
    constexpr int LPT = 2 + NI / 2;      // loads/thread/tile: A=2, W=NI/2

    __shared__ unsigned short As[4][256 * 32];
    __shared__ unsigned short Ws[4][BN * 32];

    const int tid = threadIdx.x;
    const int lane = tid & 63;
    const int warp = tid >> 6;      // 0..7
    const int wm = warp >> 2;       // 0..1
    const int wn = warp & 3;        // 0..3
    const int qm = lane & 15;
    const int quad = lane >> 4;

    // T1: bijective XCD-aware swizzle (gridDim.x % 8 == 0 for all our grids)
    const int nwg = gridDim.x;
    const int cpx = nwg >> 3;
    const int bid = blockIdx.x;
    const int swz = (bid & 7) * cpx + (bid >> 3);
    const int bx = swz % NT_N;
    const int by = swz / NT_N;
    const long arow0 = (long)by * 256;
    const long wrow0 = (long)bx * BN;

    // staging: thread covers row = i*128 + (tid>>2); source 16B-group swizzled
    const int srow = tid >> 2;                    // 0..127 (+ i*128)
    const int sgc = ((tid & 3) ^ ((srow >> 1) & 3)) * 8;   // swizzled global col

    f32x4 acc[8][NI];
    const f32x4 zero = {0.f, 0.f, 0.f, 0.f};
#pragma unroll
    for (int i = 0; i < 8; i++)
#pragma unroll
        for (int j = 0; j < NI; j++) acc[i][j] = zero;

    auto stage = [&](int buf, int k0) {
#pragma unroll
        for (int i = 0; i < 2; i++)
            async_lds16(As[buf] + i * 4096 + tid * 8,
                        A + (arow0 + i * 128 + srow) * (long)K + k0 + sgc);
#pragma unroll
        for (int i = 0; i < NI / 2; i++)
            async_lds16(Ws[buf] + i * 4096 + tid * 8,
                        W + (wrow0 + i * 128 + srow) * (long)K + k0 + sgc);
    };
    const int rgo = (quad ^ ((qm >> 1) & 3)) * 8;   // read-side swizzled group offset
    auto compute = [&](const unsigned short* Ab, const unsigned short* Wb) {
        bf16x8 fa[8], fb[NI];
#pragma unroll
        for (int mi = 0; mi < 8; mi++)
            fa[mi] = *(const bf16x8*)(Ab + (wm * 128 + mi * 16 + qm) * 32 + rgo);
#pragma unroll
        for (int ni = 0; ni < NI; ni++)
            fb[ni] = *(const bf16x8*)(Wb + (wn * (NI * 16) + ni * 16 + qm) * 32 + rgo);
#pragma unroll
        for (int mi = 0; mi < 8; mi++)
#pragma unroll
            for (int ni = 0; ni < NI; ni++)
                acc[mi][ni] = __builtin_amdgcn_mfma_f32_16x16x32_bf16(
                    fa[mi], fb[ni], acc[mi][ni], 0, 0, 0);
    };

    const int nt = K >> 5;               // 32 for K=1024
    stage(0, 0); stage(1, 32); stage(2, 64);
    waitcnt_vm<2 * LPT>(); __builtin_amdgcn_s_barrier();   // tile0 retired
    int t = 0;
    for (; t < nt - 3; ++t) {
        stage((t + 3) & 3, (t + 3) << 5);   // overwrite buf freed at iter t-1's barrier
        compute(As[t & 3], Ws[t & 3]);
        waitcnt_vm<2 * LPT>(); __builtin_amdgcn_s_barrier();   // tile t+1 retired
    }
    compute(As[t & 3], Ws[t & 3]); waitcnt_vm<LPT>(); __builtin_amdgcn_s_barrier(); ++t;
    compute(As[t & 3], Ws[t & 3]); waitcnt_vm<0>();   __builtin_amdgcn_s_barrier(); ++t;
    compute(As[t & 3], Ws[t & 3]);

    // epilogue: C/D layout col=lane&15, row=quad*4+reg (verified m89/m91)
#pragma unroll
    for (int mi = 0; mi < 8; mi++)
#pragma unroll
        for (int ni = 0; ni < NI; ni++)
#pragma unroll
            for (int r = 0; r < 4; r++) {
                const long row = arow0 + wm * 128 + mi * 16 + quad * 4 + r;
                const int col = (int)wrow0 + wn * (NI * 16) + ni * 16 + qm;
                const float v = acc[mi][ni][r];
                if (MODE == 0) {
                    ((float*)out0)[row * N + col] = v;
                } else {
                    const int seg = col >> 10, cc = col & 1023;
                    if (seg == 0) {
                        ((unsigned short*)out0)[row * 1024 + cc] = f2b(v * dtp[row * 16 + (cc >> 6)]);
                    } else if (seg == 1) {
                        out1[row * 1024 + cc] = f2b(v / (1.f + expf(-v)));
                    } else if (seg == 2) {
                        out2[row * 1024 + cc] = f2b(v);
                    } else {
                        out3[row * 1024 + cc] = f2b(v);
                    }
                }
            }
}

// ---------------- phase A (MFMA): per-chunk states -> d_out (fp32) + Alast ---------
// st[p,n] = sum_l (X[l,p]*dec[l]) * B[l,n].  Contraction over l (row of both) ->
// both operands staged TRANSPOSED in LDS. X*dec split hi/lo bf16 for fp32 fidelity.
__global__ __launch_bounds__(256) void ssd_states(
    const unsigned short* __restrict__ Xb, const unsigned short* __restrict__ Bb,
    const float* __restrict__ Ap, float* __restrict__ st_out,
    float* __restrict__ Alast)
{
    __shared__ __align__(16) unsigned short Xh[64 * 64];
    __shared__ __align__(16) unsigned short Xl[64 * 64];
    __shared__ __align__(16) unsigned short Bt[64 * 64];
    __shared__ float Acum[64];
    __shared__ float dec[64];

    const int blk = blockIdx.x;                 // blk = (b*64 + c)*16 + h
    const int h = blk & 15;
    const int c = (blk >> 4) & 63;
    const int b = blk >> 10;
    const long tokenbase = (long)b * 4096 + (long)c * 64;
    const int tid = threadIdx.x;
    const int lane = tid & 63;
    const int w = tid >> 6;
    const int qm = lane & 15;
    const int quad = lane >> 4;

    if (tid < 64) Acum[tid] = Ap[(tokenbase + tid) * 16 + h];

    // preload to regs (row-fast mapping: lane = token row, L1 soaks the stride)
    const int row = tid & 63;
    u16x8 rx[2], rb[2];
#pragma unroll
    for (int i = 0; i < 2; i++) {
        const int ch = (tid >> 6) + 4 * i;      // 0..7 over 2 iters
        const long g = (tokenbase + row) * 1024 + h * 64 + ch * 8;
        rx[i] = *(const u16x8*)(Xb + g);
        rb[i] = *(const u16x8*)(Bb + g);
    }
    __syncthreads();
    if (tid == 0) {
        float s = 0.f;
        for (int l = 0; l < 64; l++) { s += Acum[l]; Acum[l] = s; }
        Alast[(b * 16 + h) * 64 + c] = s;
    }
    __syncthreads();
    if (tid < 64) dec[tid] = expf(Acum[63] - Acum[tid]);
    __syncthreads();

    const float dv = dec[row];
#pragma unroll
    for (int i = 0; i < 2; i++) {
        const int ch = (tid >> 6) + 4 * i;
#pragma unroll
        for (int t = 0; t < 8; t++) {
            const int pn = ch * 8 + t;
            const int d = (pn * 64 + row) ^ (t << 3);   // (pn&7)==t
            const float xd = b2f(rx[i][t]) * dv;
            const unsigned short hi = f2b(xd);
            Xh[d] = hi;
            Xl[d] = f2b(xd - b2f(hi));
            Bt[d] = rb[i][t];
        }
    }
    __syncthreads();

    // wave w owns p-strip [16w, 16w+16)
    f32x4 acc[4];
    const f32x4 zero = {0.f, 0.f, 0.f, 0.f};
#pragma unroll
    for (int ni = 0; ni < 4; ni++) acc[ni] = zero;
#pragma unroll
    for (int kk2 = 0; kk2 < 2; kk2++) {
        const int ko = kk2 * 32 + quad * 8;
        const int ra = 16 * w + qm;
        const int da = (ra * 64 + ko) ^ ((ra & 7) << 3);
        bf16x8 fxh = *(const bf16x8*)(Xh + da);
        bf16x8 fxl = *(const bf16x8*)(Xl + da);
#pragma unroll
        for (int ni = 0; ni < 4; ni++) {
            const int rn = ni * 16 + qm;
            bf16x8 fb = *(const bf16x8*)(Bt + ((rn * 64 + ko) ^ ((rn & 7) << 3)));
            acc[ni] = __builtin_amdgcn_mfma_f32_16x16x32_bf16(fxh, fb, acc[ni], 0, 0, 0);
            acc[ni] = __builtin_amdgcn_mfma_f32_16x16x32_bf16(fxl, fb, acc[ni], 0, 0, 0);
        }
    }
    const long sbase = (long)blk * 4096;
    const int p0 = 16 * w + quad * 4;
#pragma unroll
    for (int ni = 0; ni < 4; ni++)
#pragma unroll
        for (int r = 0; r < 4; r++)
            st_out[sbase + (p0 + r) * 64 + ni * 16 + qm] = acc[ni][r];
}

// ---------------- inter-chunk scan (in place, fp32 in d_out) + final_state ---------
__global__ __launch_bounds__(256) void scan_kernel(
    float* __restrict__ st, const float* __restrict__ Alast)
{
    const int blk = blockIdx.x;          // 512 blocks: b(2) x h(16) x grp(16)
    const int grp = blk & 15;
    const int h = (blk >> 4) & 15;
    const int b = blk >> 8;
    const int e = grp * 256 + threadIdx.x;
    const float* al = Alast + (b * 16 + h) * 64;
    float M = 0.f;
    for (int c = 0; c < 64; c++) {
        const long idx = ((long)((b * 64 + c) * 16 + h)) * 4096 + e;
        const float s = st[idx];
        st[idx] = M;                     // state ENTERING chunk c
        M = expf(al[c]) * M + s;
    }
    st[(long)8388608 + (long)(b * 16 + h) * 4096 + e] = M;   // final_state (fp32)
}

// ---------------- phase B (MFMA): Y_diag + Y_off + silu gate (in-place into SZ) ----
// T[l,s]=sum_n C[l,n]B[s,n]; off[l,p]=sum_n C[l,n]S[p,n]; Y[l,p]=sum_s G[l,s]X[s,p].
// X staged transposed (Xt[p][s]); G written by each wave for its own strip.
__global__ __launch_bounds__(256) void ssd_yoff(
    const unsigned short* __restrict__ Xb, const unsigned short* __restrict__ Bb,
    const unsigned short* __restrict__ Cb, const float* __restrict__ Ap,
    const float* __restrict__ st, unsigned short* __restrict__ SZb)
{
    __shared__ __align__(16) unsigned short Bs[64 * 64];
    __shared__ __align__(16) unsigned short Ss[64 * 64];
    __shared__ __align__(16) unsigned short Xt[64 * 64];
    __shared__ __align__(16) unsigned short Gs[64 * 64];
    __shared__ float Acum[64];

    const int blk = blockIdx.x;
    const int h = blk & 15;
    const int c = (blk >> 4) & 63;
    const int b = blk >> 10;
    const long tokenbase = (long)b * 4096 + (long)c * 64;
    const int tid = threadIdx.x;
    const int lane = tid & 63;
    const int w = tid >> 6;
    const int qm = lane & 15;
    const int quad = lane >> 4;
    const long sbase = (long)blk * 4096;

    if (tid < 64) Acum[tid] = Ap[(tokenbase + tid) * 16 + h];

    // stage B (natural, swizzled) and S (fp32 states -> bf16, natural, swizzled)
#pragma unroll
    for (int i = 0; i < 2; i++) {
        const int idx = tid + i * 256;
        const int r8 = idx >> 3, c8 = (idx & 7) * 8;
        const long g = (tokenbase + r8) * 1024 + h * 64 + c8;
        const int d = (r8 * 64 + c8) ^ ((r8 & 7) << 3);
        *(u16x8*)(Bs + d) = *(const u16x8*)(Bb + g);
        const float* sp = st + sbase + r8 * 64 + c8;
        f32x4v s0 = *(const f32x4v*)sp, s1 = *(const f32x4v*)(sp + 4);
        u16x8 sv;
#pragma unroll
        for (int t = 0; t < 4; t++) { sv[t] = f2b(s0[t]); sv[t + 4] = f2b(s1[t]); }
        *(u16x8*)(Ss + d) = sv;
    }
    // stage Xt (transposed, row-fast mapping)
    const int xrow = tid & 63;
#pragma unroll
    for (int i = 0; i < 2; i++) {
        const int ch = (tid >> 6) + 4 * i;
        const long g = (tokenbase + xrow) * 1024 + h * 64 + ch * 8;
        u16x8 xv = *(const u16x8*)(Xb + g);
#pragma unroll
        for (int t = 0; t < 8; t++) {
            const int p = ch * 8 + t;
            Xt[(p * 64 + xrow) ^ (t << 3)] = xv[t];
        }
    }
    // C fragments direct from global (wave-private rows 16w+qm)
    u16x8 fc[2];
#pragma unroll
    for (int kk2 = 0; kk2 < 2; kk2++)
        fc[kk2] = *(const u16x8*)(Cb + (tokenbase + 16 * w + qm) * 1024 + h * 64 + kk2 * 32 + quad * 8);

    __syncthreads();
    if (tid == 0) {
        float s = 0.f;
        for (int l = 0; l < 64; l++) { s += Acum[l]; Acum[l] = s; }
    }

    // matmul1 (T = C.B^T) and matmul2 (off = C.S^T), wave strip l in [16w,16w+16)
    f32x4 acc1[4], acc2[4];
    const f32x4 zero = {0.f, 0.f, 0.f, 0.f};
#pragma unroll
    for (int ni = 0; ni < 4; ni++) { acc1[ni] = zero; acc2[ni] = zero; }
#pragma unroll
    for (int kk2 = 0; kk2 < 2; kk2++) {
        const int ko = kk2 * 32 + quad * 8;
        bf16x8 fa = *(const bf16x8*)&fc[kk2];
#pragma unroll
        for (int ni = 0; ni < 4; ni++) {
            const int rn = ni * 16 + qm;
            const int d = (rn * 64 + ko) ^ ((rn & 7) << 3);
            bf16x8 fbb = *(const bf16x8*)(Bs + d);
            acc1[ni] = __builtin_amdgcn_mfma_f32_16x16x32_bf16(fa, fbb, acc1[ni], 0, 0, 0);
            bf16x8 fbs = *(const bf16x8*)(Ss + d);
            acc2[ni] = __builtin_amdgcn_mfma_f32_16x16x32_bf16(fa, fbs, acc2[ni], 0, 0, 0);
        }
    }
    __syncthreads();   // Acum (prefix) now visible to all

    // G[l,s] = (s<=l) ? T[l,s]*exp(Acum[l]-Acum[s]) : 0  -> LDS bf16 (swizzled)
    const int l0 = 16 * w + quad * 4;
    float al[4];
#pragma unroll
    for (int r = 0; r < 4; r++) al[r] = Acum[l0 + r];
#pragma unroll
    for (int ni = 0; ni < 4; ni++) {
        const int s = ni * 16 + qm;
        const float as = Acum[s];
#pragma unroll
        for (int r = 0; r < 4; r++) {
            const int l = l0 + r;
            const float gv = (s <= l) ? acc1[ni][r] * expf(al[r] - as) : 0.f;
            Gs[(l * 64 + s) ^ ((l & 7) << 3)] = f2b(gv);
        }
    }
    __syncthreads();

    // matmul3: Y = G @ X  (A = G own strip, B = Xt)
    f32x4 acc3[4];
#pragma unroll
    for (int ni = 0; ni < 4; ni++) acc3[ni] = zero;
#pragma unroll
    for (int kk2 = 0; kk2 < 2; kk2++) {
        const int ko = kk2 * 32 + quad * 8;
        const int ra = 16 * w + qm;
        bf16x8 fg = *(const bf16x8*)(Gs + ((ra * 64 + ko) ^ ((ra & 7) << 3)));
#pragma unroll
        for (int ni = 0; ni < 4; ni++) {
            const int rp = ni * 16 + qm;
            bf16x8 fx = *(const bf16x8*)(Xt + ((rp * 64 + ko) ^ ((rp & 7) << 3)));
            acc3[ni] = __builtin_amdgcn_mfma_f32_16x16x32_bf16(fg, fx, acc3[ni], 0, 0, 0);
        }
    }
    // epilogue: Y = Y_diag + exp(Acum[l])*off; gate with silu(z) already in SZ
    float eds[4];
#pragma unroll
    for (int r = 0; r < 4; r++) eds[r] = expf(al[r]);
#pragma unroll
    for (int ni = 0; ni < 4; ni++) {
#pragma unroll
        for (int r = 0; r < 4; r++) {
            const int l = l0 + r;
            const int p = ni * 16 + qm;
            const float Y = acc3[ni][r] + eds[r] * acc2[ni][r];
            const long o = (tokenbase + l) * 1024 + h * 64 + p;
            SZb[o] = f2b(Y * b2f(SZb[o]));
        }
    }
}

// ---------------- launch -----------------------------------------------------------
extern "C" void kernel_launch(void* const* d_in, const int* in_sizes, int n_in,
                              void* d_out, int out_size, void* d_ws, size_t ws_size,
                              hipStream_t stream)
{
    int ix = 0, iwin = 1, iwdt = 2, i1m[3] = {4, 5, 6}, n1m = 0, i16[2] = {3, 7}, n16 = 0;
    for (int i = 0; i < n_in; i++) {
        switch (in_sizes[i]) {
            case 8388608: ix = i; break;
            case 2097152: iwin = i; break;
            case 16384:   iwdt = i; break;
            case 1048576: if (n1m < 3) i1m[n1m++] = i; break;
            case 16:      if (n16 < 2) i16[n16++] = i; break;
            default: break;
        }
    }
    if (n1m < 3) { i1m[0] = 4; i1m[1] = 5; i1m[2] = 6; }
    if (n16 < 2) { i16[0] = 3; i16[1] = 7; }
    const float* x     = (const float*)d_in[ix];
    const float* W_in  = (const float*)d_in[iwin];
    const float* W_dt  = (const float*)d_in[iwdt];
    const float* W_B   = (const float*)d_in[i1m[0]];
    const float* W_C   = (const float*)d_in[i1m[1]];
    const float* W_out = (const float*)d_in[i1m[2]];
    const float* s16a  = (const float*)d_in[i16[0]];
    const float* s16b  = (const float*)d_in[i16[1]];
    float* out = (float*)d_out;

    char* ws = (char*)d_ws;
    float* dtp   = (float*)(ws);                              // 512 KB @0
    float* Ap    = (float*)(ws + 524288);                     // 512 KB
    float* Alast = (float*)(ws + 1048576);                    // 8 KB
    float* Alogf = (float*)(ws + 1056768);                    // 64 B
    float* bdtf  = (float*)(ws + 1056832);                    // 64 B
    unsigned short* Xb  = (unsigned short*)(ws + 2097152);    // 16 MB
    unsigned short* Bb  = (unsigned short*)(ws + 18874368);   // 16 MB
    unsigned short* Cb  = (unsigned short*)(ws + 35651584);   // 16 MB
    unsigned short* SZb = (unsigned short*)(ws + 52428800);   // 16 MB  (end: 68 MB)

    // d_out[0:32MB) is dead until ssd_states: use it for bf16 conversions.
    // xb 16MB | stacked W bf16 [W_in(2048) ; W_B(1024) ; W_C(1024)] = 8MB -> 24MB < 32MB
    unsigned short* xb  = (unsigned short*)d_out;
    unsigned short* Wst = (unsigned short*)((char*)d_out + 16777216);
    // W_out bf16: converted AFTER ssd_yoff into the then-dead Xb ws region.
    unsigned short* Wob = Xb;

    // fp32 chunk states use d_out[0:8388608 floats) as scratch (xb/weights dead by then);
    // final_state fp32 at d_out[8388608:]; final GEMM overwrites y region.
    float* states = out;

    prep<<<6145, 256, 0, stream>>>(x, W_in, W_B, W_C, xb, Wst, s16a, s16b, Alogf, bdtf);
    dt_kernel<<<NTOK / 16, 256, 0, stream>>>(x, W_dt, bdtf, Alogf, dtp, Ap);
    // merged xz + B + C GEMM: M=8192, N=4096, K=1024; grid 32x16 = 512 blocks
    gemm256<1, 4><<<512, 512, 0, stream>>>(xb, Wst, 16, 4096, 1024, Xb, SZb, Bb, Cb, dtp);
    ssd_states<<<2048, 256, 0, stream>>>(Xb, Bb, Ap, states, Alast);
    scan_kernel<<<512, 256, 0, stream>>>(states, Alast);
    ssd_yoff<<<2048, 256, 0, stream>>>(Xb, Bb, Cb, Ap, states, SZb);
    f32_to_bf16<<<512, 256, 0, stream>>>(W_out, Wob, 131072);         // W_out -> bf16 (Xb dead)
    // final GEMM: M=8192, N=1024, K=1024, BN=128; grid 32x8 = 256 blocks (1 full round)
    gemm256<0, 2><<<256, 512, 0, stream>>>(SZb, Wob, 8, 1024, 1024, out, nullptr, nullptr, nullptr, nullptr);
}

// Round 8
// 366.745 us; speedup vs baseline: 1.1025x; 1.0371x over previous
//
#include <hip/hip_runtime.h>
#include <cstdint>
#include <cstddef>

#define NTOK 8192       // b*L = 2*4096

typedef __bf16 bf16x8 __attribute__((ext_vector_type(8)));
typedef float f32x4 __attribute__((ext_vector_type(4)));
typedef float f32x4v __attribute__((ext_vector_type(4)));
typedef unsigned short u16x8 __attribute__((ext_vector_type(8)));

__device__ __forceinline__ float b2f(unsigned short u) {
    return __uint_as_float(((unsigned int)u) << 16);
}
__device__ __forceinline__ unsigned short f2b(float f) {
    unsigned int u = __float_as_uint(f);
    u += 0x7FFFu + ((u >> 16) & 1u);   // round-nearest-even
    return (unsigned short)(u >> 16);
}

// async global->LDS, 16B per lane. LDS dest must be wave-uniform base + lane*16.
__device__ __forceinline__ void async_lds16(unsigned short* lds, const unsigned short* g) {
    __builtin_amdgcn_global_load_lds(
        (const __attribute__((address_space(1))) unsigned int*)g,
        (__attribute__((address_space(3))) unsigned int*)lds,
        16, 0, 0);
}

// ---- fused prep: x/W_in/W_B/W_C -> bf16 + scalars16 resolve (one launch) ----------
__global__ __launch_bounds__(256) void prep(
    const float* __restrict__ x, const float* __restrict__ W_in,
    const float* __restrict__ W_B, const float* __restrict__ W_C,
    unsigned short* __restrict__ xb, unsigned short* __restrict__ Wst,
    const float* __restrict__ s16a, const float* __restrict__ s16b,
    float* __restrict__ alogf, float* __restrict__ bdtf)
{
    const long i = (long)blockIdx.x * 256 + threadIdx.x;
    const float* src; unsigned short* dst; long off;
    if (i < 1048576)      { src = x;    dst = xb;            off = i; }
    else if (i < 1310720) { src = W_in; dst = Wst;           off = i - 1048576; }
    else if (i < 1441792) { src = W_B;  dst = Wst + 2097152; off = i - 1310720; }
    else if (i < 1572864) { src = W_C;  dst = Wst + 3145728; off = i - 1441792; }
    else {
        if (i == 1572864) {   // block 6144, thread 0: resolve A_log vs b_dt
            float ma = 0.f, mb = 0.f;
            for (int k = 0; k < 16; k++) { ma = fmaxf(ma, fabsf(s16a[k])); mb = fmaxf(mb, fabsf(s16b[k])); }
            const float* alog = (ma >= mb) ? s16a : s16b;
            const float* bdt  = (ma >= mb) ? s16b : s16a;
            for (int k = 0; k < 16; k++) { alogf[k] = alog[k]; bdtf[k] = bdt[k]; }
        }
        return;
    }
    const f32x4v* p = (const f32x4v*)(src + off * 8);
    f32x4v a = p[0], b = p[1];
    u16x8 v;
#pragma unroll
    for (int t = 0; t < 4; t++) { v[t] = f2b(a[t]); v[t + 4] = f2b(b[t]); }
    *(u16x8*)(dst + off * 8) = v;
}

// ---- fp32 -> bf16 bulk convert (8 elems/thread) — used for W_out ------------------
__global__ __launch_bounds__(256) void f32_to_bf16(
    const float* __restrict__ in, unsigned short* __restrict__ out, int n8)
{
    const int i = blockIdx.x * 256 + threadIdx.x;
    if (i >= n8) return;
    const f32x4v* p = (const f32x4v*)(in + (long)i * 8);
    f32x4v a = p[0], b = p[1];
    u16x8 v;
#pragma unroll
    for (int t = 0; t < 4; t++) { v[t] = f2b(a[t]); v[t + 4] = f2b(b[t]); }
    *(u16x8*)(out + (long)i * 8) = v;
}

// ---------------- dt kernel: one thread per (token, head), fp32, float4 loads ------
__global__ __launch_bounds__(256) void dt_kernel(
    const float* __restrict__ x, const float* __restrict__ Wdt,
    const float* __restrict__ bdt, const float* __restrict__ Alog,
    float* __restrict__ dtp, float* __restrict__ Ap)
{
    const int token = blockIdx.x * 16 + (threadIdx.x >> 4);
    const int h = threadIdx.x & 15;
    const f32x4v* xr = (const f32x4v*)(x + (long)token * 1024);
    const f32x4v* wr = (const f32x4v*)(Wdt + h * 1024);
    float s0 = bdt[h], s1 = 0.f;
#pragma unroll 8
    for (int k = 0; k < 256; k += 2) {
        f32x4v a0 = xr[k], w0 = wr[k];
        f32x4v a1 = xr[k + 1], w1 = wr[k + 1];
        s0 += a0[0] * w0[0] + a0[1] * w0[1] + a0[2] * w0[2] + a0[3] * w0[3];
        s1 += a1[0] * w1[0] + a1[1] * w1[1] + a1[2] * w1[2] + a1[3] * w1[3];
    }
    const float s = s0 + s1;
    const float dtv = (s > 15.f) ? s : log1pf(expf(s));
    dtp[token * 16 + h] = dtv;
    Ap[token * 16 + h] = -expf(Alog[h]) * dtv;
}

// ------- 256xBN-tile BK=64 2-phase double-buffered MFMA GEMM (round-5 verified) ----
// Out[M,N] = A[M,K] @ W[N,K]^T.  512 threads = 8 waves (2M x 4N); NI=4 -> BN=256
// (wave owns 128x64, LDS 128KB), NI=2 -> BN=128 (wave owns 128x32, LDS 96KB).
// T2 swizzle (both-sides involution on 16B groups): write = linear LDS dest
// (global_load_lds), source group (tid&7)^(srow&7); read XORs elem addr with
// (qm&7)<<3.  Measured: SQ_LDS_BANK_CONFLICT = 0, bit-identical math.
// MODE 0: fp32 out0 (stride N).
// MODE 1 (merged xz+BC over stacked W = [W_in; W_B; W_C], N=4096):
//   seg0: X = acc*dt (bf16 out0); seg1: SZ = silu (out1); seg2: Bb (out2); seg3: Cb (out3)
template <int MODE, int NI>
__global__ __launch_bounds__(512, 2) void gemm256(
    const unsigned short* __restrict__ A, const unsigned short* __restrict__ W,
    const int NT_N, const int N, const int K,
    void* __restrict__ out0, unsigned short* __restrict__ out1,
    unsigned short* __restrict__ out2, unsigned short* __restrict__ out3,
    const float* __restrict__ dtp)
{
    constexpr int BN = NI * 64;          // 256 or 128

    __shared__ unsigned short As[2][256 * 64];
    __shared__ unsigned short Ws[2][BN * 64];

    const int tid = threadIdx.x;
    const int lane = tid & 63;
    const int warp = tid >> 6;      // 0..7
    const int wm = warp >> 2;       // 0..1
    const int wn = warp & 3;        // 0..3
    const int qm = lane & 15;
    const int quad = lane >> 4;

    // T1: bijective XCD-aware swizzle (gridDim.x % 8 == 0 for all our grids)
    const int nwg = gridDim.x;
    const int cpx = nwg >> 3;
    const int bid = blockIdx.x;
    const int swz = (bid & 7) * cpx + (bid >> 3);
    const int bx = swz % NT_N;
    const int by = swz / NT_N;
    const long arow0 = (long)by * 256;
    const long wrow0 = (long)bx * BN;

    const int srow = tid >> 3;          // 0..63 (linear LDS dest = tid*16B)
    // pre-swizzled global source column (involution: group ^ (row&7))
    const int sgc = ((tid & 7) ^ (srow & 7)) * 8;

    f32x4 acc[8][NI];
    const f32x4 zero = {0.f, 0.f, 0.f, 0.f};
#pragma unroll
    for (int i = 0; i < 8; i++)
#pragma unroll
        for (int j = 0; j < NI; j++) acc[i][j] = zero;

    auto stage = [&](int buf, int k0) {
#pragma unroll
        for (int r = 0; r < 4; r++)
            async_lds16(As[buf] + r * 4096 + tid * 8,
                        A + (arow0 + r * 64 + srow) * (long)K + k0 + sgc);
#pragma unroll
        for (int r = 0; r < NI; r++)
            async_lds16(Ws[buf] + r * 4096 + tid * 8,
                        W + (wrow0 + r * 64 + srow) * (long)K + k0 + sgc);
    };
    const int rx = (qm & 7) << 3;       // read-side swizzle (row&7 == qm&7 for all frags)
    auto compute = [&](const unsigned short* Ab, const unsigned short* Wb) {
#pragma unroll
        for (int kk = 0; kk < 64; kk += 32) {
            bf16x8 fa[8], fb[NI];
#pragma unroll
            for (int mi = 0; mi < 8; mi++) {
                const int row = wm * 128 + mi * 16 + qm;
                fa[mi] = *(const bf16x8*)(Ab + ((row * 64 + kk + quad * 8) ^ rx));
            }
#pragma unroll
            for (int ni = 0; ni < NI; ni++) {
                const int row = wn * (NI * 16) + ni * 16 + qm;
                fb[ni] = *(const bf16x8*)(Wb + ((row * 64 + kk + quad * 8) ^ rx));
            }
#pragma unroll
            for (int mi = 0; mi < 8; mi++)
#pragma unroll
                for (int ni = 0; ni < NI; ni++)
                    acc[mi][ni] = __builtin_amdgcn_mfma_f32_16x16x32_bf16(
                        fa[mi], fb[ni], acc[mi][ni], 0, 0, 0);
        }
    };

    const int nk = K >> 6;
    int cur = 0;
    stage(0, 0);
    __syncthreads();                     // drains vmcnt -> buf0 ready
    for (int t = 1; t < nk; t++) {
        stage(cur ^ 1, t << 6);          // issue next tile (async, in flight during MFMA)
        compute(As[cur], Ws[cur]);
        __syncthreads();                 // drains staged loads + guards buf reuse
        cur ^= 1;
    }
    compute(As[cur], Ws[cur]);

    // epilogue: C/D layout col=lane&15, row=quad*4+reg (verified m89/m91)
#pragma unroll
    for (int mi = 0; mi < 8; mi++)
#pragma unroll
        for (int ni = 0; ni < NI; ni++)
#pragma unroll
            for (int r = 0; r < 4; r++) {
                const long row = arow0 + wm * 128 + mi * 16 + quad * 4 + r;
                const int col = (int)wrow0 + wn * (NI * 16) + ni * 16 + qm;
                const float v = acc[mi][ni][r];
                if (MODE == 0) {
                    ((float*)out0)[row * N + col] = v;
                } else {
                    const int seg = col >> 10, cc = col & 1023;
                    if (seg == 0) {
                        ((unsigned short*)out0)[row * 1024 + cc] = f2b(v * dtp[row * 16 + (cc >> 6)]);
                    } else if (seg == 1) {
                        out1[row * 1024 + cc] = f2b(v / (1.f + expf(-v)));
                    } else if (seg == 2) {
                        out2[row * 1024 + cc] = f2b(v);
                    } else {
                        out3[row * 1024 + cc] = f2b(v);
                    }
                }
            }
}

// ---------------- phase A (MFMA): per-chunk states -> d_out (fp32) + Alast ---------
// st[p,n] = sum_l (X[l,p]*dec[l]) * B[l,n].  Contraction over l (row of both) ->
// both operands staged TRANSPOSED in LDS. X*dec split hi/lo bf16 for fp32 fidelity.
// Acum prefix: wave-0 Kogge-Stone shfl scan (replaces tid0 serial 64-iter chain).
__global__ __launch_bounds__(256) void ssd_states(
    const unsigned short* __restrict__ Xb, const unsigned short* __restrict__ Bb,
    const float* __restrict__ Ap, float* __restrict__ st_out,
    float* __restrict__ Alast)
{
    __shared__ __align__(16) unsigned short Xh[64 * 64];
    __shared__ __align__(16) unsigned short Xl[64 * 64];
    __shared__ __align__(16) unsigned short Bt[64 * 64];
    __shared__ float dec[64];

    const int blk = blockIdx.x;                 // blk = (b*64 + c)*16 + h
    const int h = blk & 15;
    const int c = (blk >> 4) & 63;
    const int b = blk >> 10;
    const long tokenbase = (long)b * 4096 + (long)c * 64;
    const int tid = threadIdx.x;
    const int lane = tid & 63;
    const int w = tid >> 6;
    const int qm = lane & 15;
    const int quad = lane >> 4;

    // preload to regs (row-fast mapping: lane = token row, L1 soaks the stride)
    const int row = tid & 63;
    u16x8 rx[2], rb[2];
#pragma unroll
    for (int i = 0; i < 2; i++) {
        const int ch = (tid >> 6) + 4 * i;      // 0..7 over 2 iters
        const long g = (tokenbase + row) * 1024 + h * 64 + ch * 8;
        rx[i] = *(const u16x8*)(Xb + g);
        rb[i] = *(const u16x8*)(Bb + g);
    }
    // wave 0: inclusive prefix scan of A -> dec[], Alast
    if (tid < 64) {
        float v = Ap[(tokenbase + tid) * 16 + h];
#pragma unroll
        for (int off = 1; off < 64; off <<= 1) {
            const float u = __shfl_up(v, off, 64);
            if (tid >= off) v += u;
        }
        const float tot = __shfl(v, 63, 64);
        dec[tid] = expf(tot - v);
        if (tid == 63) Alast[(b * 16 + h) * 64 + c] = v;
    }
    __syncthreads();

    const float dv = dec[row];
#pragma unroll
    for (int i = 0; i < 2; i++) {
        const int ch = (tid >> 6) + 4 * i;
#pragma unroll
        for (int t = 0; t < 8; t++) {
            const int pn = ch * 8 + t;
            const int d = (pn * 64 + row) ^ (t << 3);   // (pn&7)==t
            const float xd = b2f(rx[i][t]) * dv;
            const unsigned short hi = f2b(xd);
            Xh[d] = hi;
            Xl[d] = f2b(xd - b2f(hi));
            Bt[d] = rb[i][t];
        }
    }
    __syncthreads();

    // wave w owns p-strip [16w, 16w+16)
    f32x4 acc[4];
    const f32x4 zero = {0.f, 0.f, 0.f, 0.f};
#pragma unroll
    for (int ni = 0; ni < 4; ni++) acc[ni] = zero;
#pragma unroll
    for (int kk2 = 0; kk2 < 2; kk2++) {
        const int ko = kk2 * 32 + quad * 8;
        const int ra = 16 * w + qm;
        const int da = (ra * 64 + ko) ^ ((ra & 7) << 3);
        bf16x8 fxh = *(const bf16x8*)(Xh + da);
        bf16x8 fxl = *(const bf16x8*)(Xl + da);
#pragma unroll
        for (int ni = 0; ni < 4; ni++) {
            const int rn = ni * 16 + qm;
            bf16x8 fb = *(const bf16x8*)(Bt + ((rn * 64 + ko) ^ ((rn & 7) << 3)));
            acc[ni] = __builtin_amdgcn_mfma_f32_16x16x32_bf16(fxh, fb, acc[ni], 0, 0, 0);
            acc[ni] = __builtin_amdgcn_mfma_f32_16x16x32_bf16(fxl, fb, acc[ni], 0, 0, 0);
        }
    }
    const long sbase = (long)blk * 4096;
    const int p0 = 16 * w + quad * 4;
#pragma unroll
    for (int ni = 0; ni < 4; ni++)
#pragma unroll
        for (int r = 0; r < 4; r++)
            st_out[sbase + (p0 + r) * 64 + ni * 16 + qm] = acc[ni][r];
}

// ---------------- inter-chunk scan (in place, fp32 in d_out) + final_state ---------
__global__ __launch_bounds__(256) void scan_kernel(
    float* __restrict__ st, const float* __restrict__ Alast)
{
    __shared__ float eal[64];
    const int blk = blockIdx.x;          // 512 blocks: b(2) x h(16) x grp(16)
    const int grp = blk & 15;
    const int h = (blk >> 4) & 15;
    const int b = blk >> 8;
    const int e = grp * 256 + threadIdx.x;
    const float* al = Alast + (b * 16 + h) * 64;
    if (threadIdx.x < 64) eal[threadIdx.x] = expf(al[threadIdx.x]);
    __syncthreads();
    float M = 0.f;
    for (int c = 0; c < 64; c++) {
        const long idx = ((long)((b * 64 + c) * 16 + h)) * 4096 + e;
        const float s = st[idx];
        st[idx] = M;                     // state ENTERING chunk c
        M = eal[c] * M + s;
    }
    st[(long)8388608 + (long)(b * 16 + h) * 4096 + e] = M;   // final_state (fp32)
}

// ---------------- phase B (MFMA): Y_diag + Y_off + silu gate (in-place into SZ) ----
// T[l,s]=sum_n C[l,n]B[s,n]; off[l,p]=sum_n C[l,n]S[p,n]; Y[l,p]=sum_s G[l,s]X[s,p].
// X staged transposed (Xt[p][s]); G written by each wave for its own strip.
// Acum prefix: wave-0 shfl scan issued before staging; one barrier covers both.
__global__ __launch_bounds__(256) void ssd_yoff(
    const unsigned short* __restrict__ Xb, const unsigned short* __restrict__ Bb,
    const unsigned short* __restrict__ Cb, const float* __restrict__ Ap,
    const float* __restrict__ st, unsigned short* __restrict__ SZb)
{
    __shared__ __align__(16) unsigned short Bs[64 * 64];
    __shared__ __align__(16) unsigned short Ss[64 * 64];
    __shared__ __align__(16) unsigned short Xt[64 * 64];
    __shared__ __align__(16) unsigned short Gs[64 * 64];
    __shared__ float Acum[64];

    const int blk = blockIdx.x;
    const int h = blk & 15;
    const int c = (blk >> 4) & 63;
    const int b = blk >> 10;
    const long tokenbase = (long)b * 4096 + (long)c * 64;
    const int tid = threadIdx.x;
    const int lane = tid & 63;
    const int w = tid >> 6;
    const int qm = lane & 15;
    const int quad = lane >> 4;
    const long sbase = (long)blk * 4096;

    // wave 0: inclusive prefix scan of A -> Acum
    if (tid < 64) {
        float v = Ap[(tokenbase + tid) * 16 + h];
#pragma unroll
        for (int off = 1; off < 64; off <<= 1) {
            const float u = __shfl_up(v, off, 64);
            if (tid >= off) v += u;
        }
        Acum[tid] = v;
    }

    // stage B (natural, swizzled) and S (fp32 states -> bf16, natural, swizzled)
#pragma unroll
    for (int i = 0; i < 2; i++) {
        const int idx = tid + i * 256;
        const int r8 = idx >> 3, c8 = (idx & 7) * 8;
        const long g = (tokenbase + r8) * 1024 + h * 64 + c8;
        const int d = (r8 * 64 + c8) ^ ((r8 & 7) << 3);
        *(u16x8*)(Bs + d) = *(const u16x8*)(Bb + g);
        const float* sp = st + sbase + r8 * 64 + c8;
        f32x4v s0 = *(const f32x4v*)sp, s1 = *(const f32x4v*)(sp + 4);
        u16x8 sv;
#pragma unroll
        for (int t = 0; t < 4; t++) { sv[t] = f2b(s0[t]); sv[t + 4] = f2b(s1[t]); }
        *(u16x8*)(Ss + d) = sv;
    }
    // stage Xt (transposed, row-fast mapping)
    const int xrow = tid & 63;
#pragma unroll
    for (int i = 0; i < 2; i++) {
        const int ch = (tid >> 6) + 4 * i;
        const long g = (tokenbase + xrow) * 1024 + h * 64 + ch * 8;
        u16x8 xv = *(const u16x8*)(Xb + g);
#pragma unroll
        for (int t = 0; t < 8; t++) {
            const int p = ch * 8 + t;
            Xt[(p * 64 + xrow) ^ (t << 3)] = xv[t];
        }
    }
    // C fragments direct from global (wave-private rows 16w+qm)
    u16x8 fc[2];
#pragma unroll
    for (int kk2 = 0; kk2 < 2; kk2++)
        fc[kk2] = *(const u16x8*)(Cb + (tokenbase + 16 * w + qm) * 1024 + h * 64 + kk2 * 32 + quad * 8);

    __syncthreads();   // staging + Acum visible

    // matmul1 (T = C.B^T) and matmul2 (off = C.S^T), wave strip l in [16w,16w+16)
    f32x4 acc1[4], acc2[4];
    const f32x4 zero = {0.f, 0.f, 0.f, 0.f};
#pragma unroll
    for (int ni = 0; ni < 4; ni++) { acc1[ni] = zero; acc2[ni] = zero; }
#pragma unroll
    for (int kk2 = 0; kk2 < 2; kk2++) {
        const int ko = kk2 * 32 + quad * 8;
        bf16x8 fa = *(const bf16x8*)&fc[kk2];
#pragma unroll
        for (int ni = 0; ni < 4; ni++) {
            const int rn = ni * 16 + qm;
            const int d = (rn * 64 + ko) ^ ((rn & 7) << 3);
            bf16x8 fbb = *(const bf16x8*)(Bs + d);
            acc1[ni] = __builtin_amdgcn_mfma_f32_16x16x32_bf16(fa, fbb, acc1[ni], 0, 0, 0);
            bf16x8 fbs = *(const bf16x8*)(Ss + d);
            acc2[ni] = __builtin_amdgcn_mfma_f32_16x16x32_bf16(fa, fbs, acc2[ni], 0, 0, 0);
        }
    }

    // G[l,s] = (s<=l) ? T[l,s]*exp(Acum[l]-Acum[s]) : 0  -> LDS bf16 (swizzled)
    // (Gs is a separate buffer; no barrier needed between matmul1 and this write)
    const int l0 = 16 * w + quad * 4;
    float al[4];
#pragma unroll
    for (int r = 0; r < 4; r++) al[r] = Acum[l0 + r];
#pragma unroll
    for (int ni = 0; ni < 4; ni++) {
        const int s = ni * 16 + qm;
        const float as = Acum[s];
#pragma unroll
        for (int r = 0; r < 4; r++) {
            const int l = l0 + r;
            const float gv = (s <= l) ? acc1[ni][r] * expf(al[r] - as) : 0.f;
            Gs[(l * 64 + s) ^ ((l & 7) << 3)] = f2b(gv);
        }
    }
    __syncthreads();   // all G strips written

    // matmul3: Y = G @ X  (A = G own strip, B = Xt)
    f32x4 acc3[4];
#pragma unroll
    for (int ni = 0; ni < 4; ni++) acc3[ni] = zero;
#pragma unroll
    for (int kk2 = 0; kk2 < 2; kk2++) {
        const int ko = kk2 * 32 + quad * 8;
        const int ra = 16 * w + qm;
        bf16x8 fg = *(const bf16x8*)(Gs + ((ra * 64 + ko) ^ ((ra & 7) << 3)));
#pragma unroll
        for (int ni = 0; ni < 4; ni++) {
            const int rp = ni * 16 + qm;
            bf16x8 fx = *(const bf16x8*)(Xt + ((rp * 64 + ko) ^ ((rp & 7) << 3)));
            acc3[ni] = __builtin_amdgcn_mfma_f32_16x16x32_bf16(fg, fx, acc3[ni], 0, 0, 0);
        }
    }
    // epilogue: Y = Y_diag + exp(Acum[l])*off; gate with silu(z) already in SZ
    float eds[4];
#pragma unroll
    for (int r = 0; r < 4; r++) eds[r] = expf(al[r]);
#pragma unroll
    for (int ni = 0; ni < 4; ni++) {
#pragma unroll
        for (int r = 0; r < 4; r++) {
            const int l = l0 + r;
            const int p = ni * 16 + qm;
            const float Y = acc3[ni][r] + eds[r] * acc2[ni][r];
            const long o = (tokenbase + l) * 1024 + h * 64 + p;
            SZb[o] = f2b(Y * b2f(SZb[o]));
        }
    }
}

// ---------------- launch -----------------------------------------------------------
extern "C" void kernel_launch(void* const* d_in, const int* in_sizes, int n_in,
                              void* d_out, int out_size, void* d_ws, size_t ws_size,
                              hipStream_t stream)
{
    int ix = 0, iwin = 1, iwdt = 2, i1m[3] = {4, 5, 6}, n1m = 0, i16[2] = {3, 7}, n16 = 0;
    for (int i = 0; i < n_in; i++) {
        switch (in_sizes[i]) {
            case 8388608: ix = i; break;
            case 2097152: iwin = i; break;
            case 16384:   iwdt = i; break;
            case 1048576: if (n1m < 3) i1m[n1m++] = i; break;
            case 16:      if (n16 < 2) i16[n16++] = i; break;
            default: break;
        }
    }
    if (n1m < 3) { i1m[0] = 4; i1m[1] = 5; i1m[2] = 6; }
    if (n16 < 2) { i16[0] = 3; i16[1] = 7; }
    const float* x     = (const float*)d_in[ix];
    const float* W_in  = (const float*)d_in[iwin];
    const float* W_dt  = (const float*)d_in[iwdt];
    const float* W_B   = (const float*)d_in[i1m[0]];
    const float* W_C   = (const float*)d_in[i1m[1]];
    const float* W_out = (const float*)d_in[i1m[2]];
    const float* s16a  = (const float*)d_in[i16[0]];
    const float* s16b  = (const float*)d_in[i16[1]];
    float* out = (float*)d_out;

    char* ws = (char*)d_ws;
    float* dtp   = (float*)(ws);                              // 512 KB @0
    float* Ap    = (float*)(ws + 524288);                     // 512 KB
    float* Alast = (float*)(ws + 1048576);                    // 8 KB
    float* Alogf = (float*)(ws + 1056768);                    // 64 B
    float* bdtf  = (float*)(ws + 1056832);                    // 64 B
    unsigned short* Xb  = (unsigned short*)(ws + 2097152);    // 16 MB
    unsigned short* Bb  = (unsigned short*)(ws + 18874368);   // 16 MB
    unsigned short* Cb  = (unsigned short*)(ws + 35651584);   // 16 MB
    unsigned short* SZb = (unsigned short*)(ws + 52428800);   // 16 MB  (end: 68 MB)

    // d_out[0:32MB) is dead until ssd_states: use it for bf16 conversions.
    // xb 16MB | stacked W bf16 [W_in(2048) ; W_B(1024) ; W_C(1024)] = 8MB -> 24MB < 32MB
    unsigned short* xb  = (unsigned short*)d_out;
    unsigned short* Wst = (unsigned short*)((char*)d_out + 16777216);
    // W_out bf16: converted AFTER ssd_yoff into the then-dead Xb ws region.
    unsigned short* Wob = Xb;

    // fp32 chunk states use d_out[0:8388608 floats) as scratch (xb/weights dead by then);
    // final_state fp32 at d_out[8388608:]; final GEMM overwrites y region.
    float* states = out;

    prep<<<6145, 256, 0, stream>>>(x, W_in, W_B, W_C, xb, Wst, s16a, s16b, Alogf, bdtf);
    dt_kernel<<<NTOK / 16, 256, 0, stream>>>(x, W_dt, bdtf, Alogf, dtp, Ap);
    // merged xz + B + C GEMM: M=8192, N=4096, K=1024; grid 32x16 = 512 blocks
    gemm256<1, 4><<<512, 512, 0, stream>>>(xb, Wst, 16, 4096, 1024, Xb, SZb, Bb, Cb, dtp);
    ssd_states<<<2048, 256, 0, stream>>>(Xb, Bb, Ap, states, Alast);
    scan_kernel<<<512, 256, 0, stream>>>(states, Alast);
    ssd_yoff<<<2048, 256, 0, stream>>>(Xb, Bb, Cb, Ap, states, SZb);
    f32_to_bf16<<<512, 256, 0, stream>>>(W_out, Wob, 131072);         // W_out -> bf16 (Xb dead)
    // final GEMM: M=8192, N=1024, K=1024, BN=128; grid 32x8 = 256 blocks (1 full round)
    gemm256<0, 2><<<256, 512, 0, stream>>>(SZb, Wob, 8, 1024, 1024, out, nullptr, nullptr, nullptr, nullptr);
}

// Round 9
// 357.338 us; speedup vs baseline: 1.1316x; 1.0263x over previous
//
#include <hip/hip_runtime.h>
#include <cstdint>
#include <cstddef>

#define NTOK 8192       // b*L = 2*4096

typedef __bf16 bf16x8 __attribute__((ext_vector_type(8)));
typedef float f32x4 __attribute__((ext_vector_type(4)));
typedef float f32x4v __attribute__((ext_vector_type(4)));
typedef unsigned short u16x8 __attribute__((ext_vector_type(8)));

__device__ __forceinline__ float b2f(unsigned short u) {
    return __uint_as_float(((unsigned int)u) << 16);
}
__device__ __forceinline__ unsigned short f2b(float f) {
    unsigned int u = __float_as_uint(f);
    u += 0x7FFFu + ((u >> 16) & 1u);   // round-nearest-even
    return (unsigned short)(u >> 16);
}

// async global->LDS, 16B per lane. LDS dest must be wave-uniform base + lane*16.
__device__ __forceinline__ void async_lds16(unsigned short* lds, const unsigned short* g) {
    __builtin_amdgcn_global_load_lds(
        (const __attribute__((address_space(1))) unsigned int*)g,
        (__attribute__((address_space(3))) unsigned int*)lds,
        16, 0, 0);
}

template <int N> __device__ __forceinline__ void waitcnt_vm() {
    if constexpr (N == 8)      asm volatile("s_waitcnt vmcnt(8)" ::: "memory");
    else if constexpr (N == 6) asm volatile("s_waitcnt vmcnt(6)" ::: "memory");
    else                       asm volatile("s_waitcnt vmcnt(0)" ::: "memory");
}

// ---- fused prep: x/W_in/W_B/W_C -> bf16 + scalars16 resolve (one launch) ----------
__global__ __launch_bounds__(256) void prep(
    const float* __restrict__ x, const float* __restrict__ W_in,
    const float* __restrict__ W_B, const float* __restrict__ W_C,
    unsigned short* __restrict__ xb, unsigned short* __restrict__ Wst,
    const float* __restrict__ s16a, const float* __restrict__ s16b,
    float* __restrict__ alogf, float* __restrict__ bdtf)
{
    const long i = (long)blockIdx.x * 256 + threadIdx.x;
    const float* src; unsigned short* dst; long off;
    if (i < 1048576)      { src = x;    dst = xb;            off = i; }
    else if (i < 1310720) { src = W_in; dst = Wst;           off = i - 1048576; }
    else if (i < 1441792) { src = W_B;  dst = Wst + 2097152; off = i - 1310720; }
    else if (i < 1572864) { src = W_C;  dst = Wst + 3145728; off = i - 1441792; }
    else {
        if (i == 1572864) {   // block 6144, thread 0: resolve A_log vs b_dt
            float ma = 0.f, mb = 0.f;
            for (int k = 0; k < 16; k++) { ma = fmaxf(ma, fabsf(s16a[k])); mb = fmaxf(mb, fabsf(s16b[k])); }
            const float* alog = (ma >= mb) ? s16a : s16b;
            const float* bdt  = (ma >= mb) ? s16b : s16a;
            for (int k = 0; k < 16; k++) { alogf[k] = alog[k]; bdtf[k] = bdt[k]; }
        }
        return;
    }
    const f32x4v* p = (const f32x4v*)(src + off * 8);
    f32x4v a = p[0], b = p[1];
    u16x8 v;
#pragma unroll
    for (int t = 0; t < 4; t++) { v[t] = f2b(a[t]); v[t + 4] = f2b(b[t]); }
    *(u16x8*)(dst + off * 8) = v;
}

// ---- fp32 -> bf16 bulk convert (8 elems/thread) — used for W_out ------------------
__global__ __launch_bounds__(256) void f32_to_bf16(
    const float* __restrict__ in, unsigned short* __restrict__ out, int n8)
{
    const int i = blockIdx.x * 256 + threadIdx.x;
    if (i >= n8) return;
    const f32x4v* p = (const f32x4v*)(in + (long)i * 8);
    f32x4v a = p[0], b = p[1];
    u16x8 v;
#pragma unroll
    for (int t = 0; t < 4; t++) { v[t] = f2b(a[t]); v[t + 4] = f2b(b[t]); }
    *(u16x8*)(out + (long)i * 8) = v;
}

// ---------------- dt kernel: one thread per (token, head), fp32, float4 loads ------
__global__ __launch_bounds__(256) void dt_kernel(
    const float* __restrict__ x, const float* __restrict__ Wdt,
    const float* __restrict__ bdt, const float* __restrict__ Alog,
    float* __restrict__ dtp, float* __restrict__ Ap)
{
    const int token = blockIdx.x * 16 + (threadIdx.x >> 4);
    const int h = threadIdx.x & 15;
    const f32x4v* xr = (const f32x4v*)(x + (long)token * 1024);
    const f32x4v* wr = (const f32x4v*)(Wdt + h * 1024);
    float s0 = bdt[h], s1 = 0.f;
#pragma unroll 8
    for (int k = 0; k < 256; k += 2) {
        f32x4v a0 = xr[k], w0 = wr[k];
        f32x4v a1 = xr[k + 1], w1 = wr[k + 1];
        s0 += a0[0] * w0[0] + a0[1] * w0[1] + a0[2] * w0[2] + a0[3] * w0[3];
        s1 += a1[0] * w1[0] + a1[1] * w1[1] + a1[2] * w1[2] + a1[3] * w1[3];
    }
    const float s = s0 + s1;
    const float dtv = (s > 15.f) ? s : log1pf(expf(s));
    dtp[token * 16 + h] = dtv;
    Ap[token * 16 + h] = -expf(Alog[h]) * dtv;
}

// ------- 256xBN-tile BK=64 2-buffer, 2-tiles-ahead counted-vmcnt MFMA GEMM ---------
// Out[M,N] = A[M,K] @ W[N,K]^T.  512 threads = 8 waves (2M x 4N); NI=4 -> BN=256,
// NI=2 -> BN=128.  T2 swizzle (both-sides involution, verified conflict-free):
// write = linear LDS dest (global_load_lds), source group (tid&7)^(srow&7);
// read XORs elem addr with (qm&7)<<3.
// T4 pipeline: tiles t+1,t+2 in flight on 2 buffers. Per iteration:
//   compute(buf t) ; barrier(A: reads done) ; stage(buf t, tile t+2) ;
//   vmcnt(LPS) (retires tile t+1's loads, t+2's stay in flight) ; barrier(B: publish).
// Each stage gets ~2 compute-phases (~1200cyc) to cover ~900cyc HBM latency.
// Raw s_barrier (NOT __syncthreads -> no forced vmcnt(0) drain).
// MODE 0: fp32 out0 (stride N).
// MODE 1 (merged xz+BC over stacked W = [W_in; W_B; W_C], N=4096):
//   seg0: X = acc*dt (bf16 out0); seg1: SZ = silu (out1); seg2: Bb (out2); seg3: Cb (out3)
template <int MODE, int NI>
__global__ __launch_bounds__(512, 2) void gemm256(
    const unsigned short* __restrict__ A, const unsigned short* __restrict__ W,
    const int NT_N, const int N, const int K,
    void* __restrict__ out0, unsigned short* __restrict__ out1,
    unsigned short* __restrict__ out2, unsigned short* __restrict__ out3,
    const float* __restrict__ dtp)
{
    constexpr int BN = NI * 64;          // 256 or 128
    constexpr int LPS = 4 + NI;          // loads per stage per thread (A:4, W:NI)

    __shared__ unsigned short As[2][256 * 64];
    __shared__ unsigned short Ws[2][BN * 64];

    const int tid = threadIdx.x;
    const int lane = tid & 63;
    const int warp = tid >> 6;      // 0..7
    const int wm = warp >> 2;       // 0..1
    const int wn = warp & 3;        // 0..3
    const int qm = lane & 15;
    const int quad = lane >> 4;

    // T1: bijective XCD-aware swizzle (gridDim.x % 8 == 0 for all our grids)
    const int nwg = gridDim.x;
    const int cpx = nwg >> 3;
    const int bid = blockIdx.x;
    const int swz = (bid & 7) * cpx + (bid >> 3);
    const int bx = swz % NT_N;
    const int by = swz / NT_N;
    const long arow0 = (long)by * 256;
    const long wrow0 = (long)bx * BN;

    const int srow = tid >> 3;          // 0..63 (linear LDS dest = tid*16B)
    const int sgc = ((tid & 7) ^ (srow & 7)) * 8;   // pre-swizzled source column

    f32x4 acc[8][NI];
    const f32x4 zero = {0.f, 0.f, 0.f, 0.f};
#pragma unroll
    for (int i = 0; i < 8; i++)
#pragma unroll
        for (int j = 0; j < NI; j++) acc[i][j] = zero;

    auto stage = [&](int buf, int k0) {
#pragma unroll
        for (int r = 0; r < 4; r++)
            async_lds16(As[buf] + r * 4096 + tid * 8,
                        A + (arow0 + r * 64 + srow) * (long)K + k0 + sgc);
#pragma unroll
        for (int r = 0; r < NI; r++)
            async_lds16(Ws[buf] + r * 4096 + tid * 8,
                        W + (wrow0 + r * 64 + srow) * (long)K + k0 + sgc);
    };
    const int rx = (qm & 7) << 3;       // read-side swizzle (row&7 == qm&7 for all frags)
    auto compute = [&](const unsigned short* Ab, const unsigned short* Wb) {
#pragma unroll
        for (int kk = 0; kk < 64; kk += 32) {
            bf16x8 fa[8], fb[NI];
#pragma unroll
            for (int mi = 0; mi < 8; mi++) {
                const int row = wm * 128 + mi * 16 + qm;
                fa[mi] = *(const bf16x8*)(Ab + ((row * 64 + kk + quad * 8) ^ rx));
            }
#pragma unroll
            for (int ni = 0; ni < NI; ni++) {
                const int row = wn * (NI * 16) + ni * 16 + qm;
                fb[ni] = *(const bf16x8*)(Wb + ((row * 64 + kk + quad * 8) ^ rx));
            }
#pragma unroll
            for (int mi = 0; mi < 8; mi++)
#pragma unroll
                for (int ni = 0; ni < NI; ni++)
                    acc[mi][ni] = __builtin_amdgcn_mfma_f32_16x16x32_bf16(
                        fa[mi], fb[ni], acc[mi][ni], 0, 0, 0);
        }
    };

    const int nk = K >> 6;               // 16 for K=1024
    stage(0, 0);
    stage(1, 64);
    waitcnt_vm<LPS>();                   // tile 0 retired (tile 1's loads in flight)
    __builtin_amdgcn_s_barrier();
    for (int t = 0; t < nk; t++) {
        compute(As[t & 1], Ws[t & 1]);
        if (t + 1 < nk) {
            __builtin_amdgcn_s_barrier();            // A: all waves done reading buf t&1
            if (t + 2 < nk) {
                stage(t & 1, (t + 2) << 6);          // overwrite freed buffer
                waitcnt_vm<LPS>();                   // retires tile t+1's loads
            } else {
                waitcnt_vm<0>();                     // drain last staged tile
            }
            __builtin_amdgcn_s_barrier();            // B: publish buf (t+1)&1
        }
    }

    // epilogue: C/D layout col=lane&15, row=quad*4+reg (verified m89/m91)
#pragma unroll
    for (int mi = 0; mi < 8; mi++)
#pragma unroll
        for (int ni = 0; ni < NI; ni++)
#pragma unroll
            for (int r = 0; r < 4; r++) {
                const long row = arow0 + wm * 128 + mi * 16 + quad * 4 + r;
                const int col = (int)wrow0 + wn * (NI * 16) + ni * 16 + qm;
                const float v = acc[mi][ni][r];
                if (MODE == 0) {
                    ((float*)out0)[row * N + col] = v;
                } else {
                    const int seg = col >> 10, cc = col & 1023;
                    if (seg == 0) {
                        ((unsigned short*)out0)[row * 1024 + cc] = f2b(v * dtp[row * 16 + (cc >> 6)]);
                    } else if (seg == 1) {
                        out1[row * 1024 + cc] = f2b(v / (1.f + expf(-v)));
                    } else if (seg == 2) {
                        out2[row * 1024 + cc] = f2b(v);
                    } else {
                        out3[row * 1024 + cc] = f2b(v);
                    }
                }
            }
}

// ---------------- phase A (MFMA): per-chunk states -> d_out (fp32) + Alast ---------
// st[p,n] = sum_l (X[l,p]*dec[l]) * B[l,n].  Contraction over l (row of both) ->
// both operands staged TRANSPOSED in LDS. X*dec split hi/lo bf16 for fp32 fidelity.
// Acum prefix: wave-0 Kogge-Stone shfl scan.
__global__ __launch_bounds__(256) void ssd_states(
    const unsigned short* __restrict__ Xb, const unsigned short* __restrict__ Bb,
    const float* __restrict__ Ap, float* __restrict__ st_out,
    float* __restrict__ Alast)
{
    __shared__ __align__(16) unsigned short Xh[64 * 64];
    __shared__ __align__(16) unsigned short Xl[64 * 64];
    __shared__ __align__(16) unsigned short Bt[64 * 64];
    __shared__ float dec[64];

    const int blk = blockIdx.x;                 // blk = (b*64 + c)*16 + h
    const int h = blk & 15;
    const int c = (blk >> 4) & 63;
    const int b = blk >> 10;
    const long tokenbase = (long)b * 4096 + (long)c * 64;
    const int tid = threadIdx.x;
    const int lane = tid & 63;
    const int w = tid >> 6;
    const int qm = lane & 15;
    const int quad = lane >> 4;

    // preload to regs (row-fast mapping: lane = token row, L1 soaks the stride)
    const int row = tid & 63;
    u16x8 rx[2], rb[2];
#pragma unroll
    for (int i = 0; i < 2; i++) {
        const int ch = (tid >> 6) + 4 * i;      // 0..7 over 2 iters
        const long g = (tokenbase + row) * 1024 + h * 64 + ch * 8;
        rx[i] = *(const u16x8*)(Xb + g);
        rb[i] = *(const u16x8*)(Bb + g);
    }
    // wave 0: inclusive prefix scan of A -> dec[], Alast
    if (tid < 64) {
        float v = Ap[(tokenbase + tid) * 16 + h];
#pragma unroll
        for (int off = 1; off < 64; off <<= 1) {
            const float u = __shfl_up(v, off, 64);
            if (tid >= off) v += u;
        }
        const float tot = __shfl(v, 63, 64);
        dec[tid] = expf(tot - v);
        if (tid == 63) Alast[(b * 16 + h) * 64 + c] = v;
    }
    __syncthreads();

    const float dv = dec[row];
#pragma unroll
    for (int i = 0; i < 2; i++) {
        const int ch = (tid >> 6) + 4 * i;
#pragma unroll
        for (int t = 0; t < 8; t++) {
            const int pn = ch * 8 + t;
            const int d = (pn * 64 + row) ^ (t << 3);   // (pn&7)==t
            const float xd = b2f(rx[i][t]) * dv;
            const unsigned short hi = f2b(xd);
            Xh[d] = hi;
            Xl[d] = f2b(xd - b2f(hi));
            Bt[d] = rb[i][t];
        }
    }
    __syncthreads();

    // wave w owns p-strip [16w, 16w+16)
    f32x4 acc[4];
    const f32x4 zero = {0.f, 0.f, 0.f, 0.f};
#pragma unroll
    for (int ni = 0; ni < 4; ni++) acc[ni] = zero;
#pragma unroll
    for (int kk2 = 0; kk2 < 2; kk2++) {
        const int ko = kk2 * 32 + quad * 8;
        const int ra = 16 * w + qm;
        const int da = (ra * 64 + ko) ^ ((ra & 7) << 3);
        bf16x8 fxh = *(const bf16x8*)(Xh + da);
        bf16x8 fxl = *(const bf16x8*)(Xl + da);
#pragma unroll
        for (int ni = 0; ni < 4; ni++) {
            const int rn = ni * 16 + qm;
            bf16x8 fb = *(const bf16x8*)(Bt + ((rn * 64 + ko) ^ ((rn & 7) << 3)));
            acc[ni] = __builtin_amdgcn_mfma_f32_16x16x32_bf16(fxh, fb, acc[ni], 0, 0, 0);
            acc[ni] = __builtin_amdgcn_mfma_f32_16x16x32_bf16(fxl, fb, acc[ni], 0, 0, 0);
        }
    }
    const long sbase = (long)blk * 4096;
    const int p0 = 16 * w + quad * 4;
#pragma unroll
    for (int ni = 0; ni < 4; ni++)
#pragma unroll
        for (int r = 0; r < 4; r++)
            st_out[sbase + (p0 + r) * 64 + ni * 16 + qm] = acc[ni][r];
}

// ---------------- inter-chunk scan (in place, fp32 in d_out) + final_state ---------
// 4x unroll: batch 4 independent chunk-loads per group to cut the serial-latency
// chain 4x (FMA order unchanged -> bit-identical).
__global__ __launch_bounds__(256) void scan_kernel(
    float* __restrict__ st, const float* __restrict__ Alast)
{
    __shared__ float eal[64];
    const int blk = blockIdx.x;          // 512 blocks: b(2) x h(16) x grp(16)
    const int grp = blk & 15;
    const int h = (blk >> 4) & 15;
    const int b = blk >> 8;
    const int e = grp * 256 + threadIdx.x;
    const float* al = Alast + (b * 16 + h) * 64;
    if (threadIdx.x < 64) eal[threadIdx.x] = expf(al[threadIdx.x]);
    __syncthreads();
    const long base = ((long)(b * 64 * 16 + h)) * 4096 + e;   // c=0 index
    const long cstep = (long)16 * 4096;                        // per-chunk stride
    float M = 0.f;
    for (int c = 0; c < 64; c += 4) {
        const long i0 = base + (long)c * cstep;
        const float s0 = st[i0];
        const float s1 = st[i0 + cstep];
        const float s2 = st[i0 + 2 * cstep];
        const float s3 = st[i0 + 3 * cstep];
        st[i0] = M;              M = eal[c] * M + s0;
        st[i0 + cstep] = M;      M = eal[c + 1] * M + s1;
        st[i0 + 2 * cstep] = M;  M = eal[c + 2] * M + s2;
        st[i0 + 3 * cstep] = M;  M = eal[c + 3] * M + s3;
    }
    st[(long)8388608 + (long)(b * 16 + h) * 4096 + e] = M;   // final_state (fp32)
}

// ---------------- phase B (MFMA): Y_diag + Y_off + silu gate (in-place into SZ) ----
// T[l,s]=sum_n C[l,n]B[s,n]; off[l,p]=sum_n C[l,n]S[p,n]; Y[l,p]=sum_s G[l,s]X[s,p].
// X staged transposed (Xt[p][s]); G written by each wave for its own strip.
// Acum prefix: wave-0 shfl scan issued before staging; one barrier covers both.
__global__ __launch_bounds__(256) void ssd_yoff(
    const unsigned short* __restrict__ Xb, const unsigned short* __restrict__ Bb,
    const unsigned short* __restrict__ Cb, const float* __restrict__ Ap,
    const float* __restrict__ st, unsigned short* __restrict__ SZb)
{
    __shared__ __align__(16) unsigned short Bs[64 * 64];
    __shared__ __align__(16) unsigned short Ss[64 * 64];
    __shared__ __align__(16) unsigned short Xt[64 * 64];
    __shared__ __align__(16) unsigned short Gs[64 * 64];
    __shared__ float Acum[64];

    const int blk = blockIdx.x;
    const int h = blk & 15;
    const int c = (blk >> 4) & 63;
    const int b = blk >> 10;
    const long tokenbase = (long)b * 4096 + (long)c * 64;
    const int tid = threadIdx.x;
    const int lane = tid & 63;
    const int w = tid >> 6;
    const int qm = lane & 15;
    const int quad = lane >> 4;
    const long sbase = (long)blk * 4096;

    // wave 0: inclusive prefix scan of A -> Acum
    if (tid < 64) {
        float v = Ap[(tokenbase + tid) * 16 + h];
#pragma unroll
        for (int off = 1; off < 64; off <<= 1) {
            const float u = __shfl_up(v, off, 64);
            if (tid >= off) v += u;
        }
        Acum[tid] = v;
    }

    // stage B (natural, swizzled) and S (fp32 states -> bf16, natural, swizzled)
#pragma unroll
    for (int i = 0; i < 2; i++) {
        const int idx = tid + i * 256;
        const int r8 = idx >> 3, c8 = (idx & 7) * 8;
        const long g = (tokenbase + r8) * 1024 + h * 64 + c8;
        const int d = (r8 * 64 + c8) ^ ((r8 & 7) << 3);
        *(u16x8*)(Bs + d) = *(const u16x8*)(Bb + g);
        const float* sp = st + sbase + r8 * 64 + c8;
        f32x4v s0 = *(const f32x4v*)sp, s1 = *(const f32x4v*)(sp + 4);
        u16x8 sv;
#pragma unroll
        for (int t = 0; t < 4; t++) { sv[t] = f2b(s0[t]); sv[t + 4] = f2b(s1[t]); }
        *(u16x8*)(Ss + d) = sv;
    }
    // stage Xt (transposed, row-fast mapping)
    const int xrow = tid & 63;
#pragma unroll
    for (int i = 0; i < 2; i++) {
        const int ch = (tid >> 6) + 4 * i;
        const long g = (tokenbase + xrow) * 1024 + h * 64 + ch * 8;
        u16x8 xv = *(const u16x8*)(Xb + g);
#pragma unroll
        for (int t = 0; t < 8; t++) {
            const int p = ch * 8 + t;
            Xt[(p * 64 + xrow) ^ (t << 3)] = xv[t];
        }
    }
    // C fragments direct from global (wave-private rows 16w+qm)
    u16x8 fc[2];
#pragma unroll
    for (int kk2 = 0; kk2 < 2; kk2++)
        fc[kk2] = *(const u16x8*)(Cb + (tokenbase + 16 * w + qm) * 1024 + h * 64 + kk2 * 32 + quad * 8);

    __syncthreads();   // staging + Acum visible

    // matmul1 (T = C.B^T) and matmul2 (off = C.S^T), wave strip l in [16w,16w+16)
    f32x4 acc1[4], acc2[4];
    const f32x4 zero = {0.f, 0.f, 0.f, 0.f};
#pragma unroll
    for (int ni = 0; ni < 4; ni++) { acc1[ni] = zero; acc2[ni] = zero; }
#pragma unroll
    for (int kk2 = 0; kk2 < 2; kk2++) {
        const int ko = kk2 * 32 + quad * 8;
        bf16x8 fa = *(const bf16x8*)&fc[kk2];
#pragma unroll
        for (int ni = 0; ni < 4; ni++) {
            const int rn = ni * 16 + qm;
            const int d = (rn * 64 + ko) ^ ((rn & 7) << 3);
            bf16x8 fbb = *(const bf16x8*)(Bs + d);
            acc1[ni] = __builtin_amdgcn_mfma_f32_16x16x32_bf16(fa, fbb, acc1[ni], 0, 0, 0);
            bf16x8 fbs = *(const bf16x8*)(Ss + d);
            acc2[ni] = __builtin_amdgcn_mfma_f32_16x16x32_bf16(fa, fbs, acc2[ni], 0, 0, 0);
        }
    }

    // G[l,s] = (s<=l) ? T[l,s]*exp(Acum[l]-Acum[s]) : 0  -> LDS bf16 (swizzled)
    const int l0 = 16 * w + quad * 4;
    float al[4];
#pragma unroll
    for (int r = 0; r < 4; r++) al[r] = Acum[l0 + r];
#pragma unroll
    for (int ni = 0; ni < 4; ni++) {
        const int s = ni * 16 + qm;
        const float as = Acum[s];
#pragma unroll
        for (int r = 0; r < 4; r++) {
            const int l = l0 + r;
            const float gv = (s <= l) ? acc1[ni][r] * expf(al[r] - as) : 0.f;
            Gs[(l * 64 + s) ^ ((l & 7) << 3)] = f2b(gv);
        }
    }
    __syncthreads();   // all G strips written

    // matmul3: Y = G @ X  (A = G own strip, B = Xt)
    f32x4 acc3[4];
#pragma unroll
    for (int ni = 0; ni < 4; ni++) acc3[ni] = zero;
#pragma unroll
    for (int kk2 = 0; kk2 < 2; kk2++) {
        const int ko = kk2 * 32 + quad * 8;
        const int ra = 16 * w + qm;
        bf16x8 fg = *(const bf16x8*)(Gs + ((ra * 64 + ko) ^ ((ra & 7) << 3)));
#pragma unroll
        for (int ni = 0; ni < 4; ni++) {
            const int rp = ni * 16 + qm;
            bf16x8 fx = *(const bf16x8*)(Xt + ((rp * 64 + ko) ^ ((rp & 7) << 3)));
            acc3[ni] = __builtin_amdgcn_mfma_f32_16x16x32_bf16(fg, fx, acc3[ni], 0, 0, 0);
        }
    }
    // epilogue: Y = Y_diag + exp(Acum[l])*off; gate with silu(z) already in SZ
    float eds[4];
#pragma unroll
    for (int r = 0; r < 4; r++) eds[r] = expf(al[r]);
#pragma unroll
    for (int ni = 0; ni < 4; ni++) {
#pragma unroll
        for (int r = 0; r < 4; r++) {
            const int l = l0 + r;
            const int p = ni * 16 + qm;
            const float Y = acc3[ni][r] + eds[r] * acc2[ni][r];
            const long o = (tokenbase + l) * 1024 + h * 64 + p;
            SZb[o] = f2b(Y * b2f(SZb[o]));
        }
    }
}

// ---------------- launch -----------------------------------------------------------
extern "C" void kernel_launch(void* const* d_in, const int* in_sizes, int n_in,
                              void* d_out, int out_size, void* d_ws, size_t ws_size,
                              hipStream_t stream)
{
    int ix = 0, iwin = 1, iwdt = 2, i1m[3] = {4, 5, 6}, n1m = 0, i16[2] = {3, 7}, n16 = 0;
    for (int i = 0; i < n_in; i++) {
        switch (in_sizes[i]) {
            case 8388608: ix = i; break;
            case 2097152: iwin = i; break;
            case 16384:   iwdt = i; break;
            case 1048576: if (n1m < 3) i1m[n1m++] = i; break;
            case 16:      if (n16 < 2) i16[n16++] = i; break;
            default: break;
        }
    }
    if (n1m < 3) { i1m[0] = 4; i1m[1] = 5; i1m[2] = 6; }
    if (n16 < 2) { i16[0] = 3; i16[1] = 7; }
    const float* x     = (const float*)d_in[ix];
    const float* W_in  = (const float*)d_in[iwin];
    const float* W_dt  = (const float*)d_in[iwdt];
    const float* W_B   = (const float*)d_in[i1m[0]];
    const float* W_C   = (const float*)d_in[i1m[1]];
    const float* W_out = (const float*)d_in[i1m[2]];
    const float* s16a  = (const float*)d_in[i16[0]];
    const float* s16b  = (const float*)d_in[i16[1]];
    float* out = (float*)d_out;

    char* ws = (char*)d_ws;
    float* dtp   = (float*)(ws);                              // 512 KB @0
    float* Ap    = (float*)(ws + 524288);                     // 512 KB
    float* Alast = (float*)(ws + 1048576);                    // 8 KB
    float* Alogf = (float*)(ws + 1056768);                    // 64 B
    float* bdtf  = (float*)(ws + 1056832);                    // 64 B
    unsigned short* Xb  = (unsigned short*)(ws + 2097152);    // 16 MB
    unsigned short* Bb  = (unsigned short*)(ws + 18874368);   // 16 MB
    unsigned short* Cb  = (unsigned short*)(ws + 35651584);   // 16 MB
    unsigned short* SZb = (unsigned short*)(ws + 52428800);   // 16 MB  (end: 68 MB)

    // d_out[0:32MB) is dead until ssd_states: use it for bf16 conversions.
    // xb 16MB | stacked W bf16 [W_in(2048) ; W_B(1024) ; W_C(1024)] = 8MB -> 24MB < 32MB
    unsigned short* xb  = (unsigned short*)d_out;
    unsigned short* Wst = (unsigned short*)((char*)d_out + 16777216);
    // W_out bf16: converted AFTER ssd_yoff into the then-dead Xb ws region.
    unsigned short* Wob = Xb;

    // fp32 chunk states use d_out[0:8388608 floats) as scratch (xb/weights dead by then);
    // final_state fp32 at d_out[8388608:]; final GEMM overwrites y region.
    float* states = out;

    prep<<<6145, 256, 0, stream>>>(x, W_in, W_B, W_C, xb, Wst, s16a, s16b, Alogf, bdtf);
    dt_kernel<<<NTOK / 16, 256, 0, stream>>>(x, W_dt, bdtf, Alogf, dtp, Ap);
    // merged xz + B + C GEMM: M=8192, N=4096, K=1024; grid 32x16 = 512 blocks
    gemm256<1, 4><<<512, 512, 0, stream>>>(xb, Wst, 16, 4096, 1024, Xb, SZb, Bb, Cb, dtp);
    ssd_states<<<2048, 256, 0, stream>>>(Xb, Bb, Ap, states, Alast);
    scan_kernel<<<512, 256, 0, stream>>>(states, Alast);
    ssd_yoff<<<2048, 256, 0, stream>>>(Xb, Bb, Cb, Ap, states, SZb);
    f32_to_bf16<<<512, 256, 0, stream>>>(W_out, Wob, 131072);         // W_out -> bf16 (Xb dead)
    // final GEMM: M=8192, N=1024, K=1024, BN=128; grid 32x8 = 256 blocks (1 full round)
    gemm256<0, 2><<<256, 512, 0, stream>>>(SZb, Wob, 8, 1024, 1024, out, nullptr, nullptr, nullptr, nullptr);
}